// Round 1
// baseline (23316.467 us; speedup 1.0000x reference)
//
#include <hip/hip_runtime.h>
#include <math.h>

// ---- problem constants --------------------------------------------------
constexpr int kL = 12, kD = 768, kH = 12, kV = 51865, kSA = 1500;
constexpr int kB = 2, kT = 192, kMC = 256, kDH = 64;
constexpr float kScale = 0.125f;      // DH^-0.5
constexpr float kEps = 1e-5f;
constexpr int kR = kB * kMC;          // 512 rows through the layer stack

// ---- d_out layout (flat float32, reference return order) ---------------
constexpr size_t SZ_LOGITS = (size_t)kB * kT * kV;                  // 19,916,160
constexpr size_t SZ_CQK    = (size_t)kL * kB * kH * kT * kSA;       // 82,944,000
constexpr size_t SZ_MKV    = (size_t)2 * kL * kB * kMC * kD;        //  9,437,184
constexpr size_t OFF_CQK = SZ_LOGITS;
constexpr size_t OFF_MKV = OFF_CQK + SZ_CQK;
constexpr size_t OFF_CKV = OFF_MKV + SZ_MKV;

// ========================================================================
// embedding: h[b,t,:] = tok_emb[x[b,t]] + pos_emb[t]  (t<T), else 0 (pad)
// ========================================================================
__global__ void k_embed(const int* __restrict__ x, const float* __restrict__ tok,
                        const float* __restrict__ pos, float* __restrict__ h)
{
    int idx = blockIdx.x * 256 + threadIdx.x;       // covers kB*kMC*kD exactly
    int d = idx % kD;
    int t = (idx / kD) % kMC;
    int b = idx / (kD * kMC);
    float v = 0.f;
    if (t < kT) {
        int tokid = x[b * kT + t];
        v = tok[(size_t)tokid * kD + d] + pos[(size_t)t * kD + d];
    }
    h[idx] = v;
}

// ========================================================================
// LayerNorm, one block (256 thr) per row of 768
// ========================================================================
__global__ void k_ln(const float* __restrict__ in, const float* __restrict__ g,
                     const float* __restrict__ bb, float* __restrict__ out)
{
    int r = blockIdx.x;
    const float* xr = in + (size_t)r * kD;
    int t = threadIdx.x;
    float x0 = xr[t], x1 = xr[t + 256], x2 = xr[t + 512];
    float s  = x0 + x1 + x2;
    float sq = x0 * x0 + x1 * x1 + x2 * x2;
    __shared__ float red[8];
    for (int o = 32; o > 0; o >>= 1) { s += __shfl_down(s, o); sq += __shfl_down(sq, o); }
    int w = t >> 6;
    if ((t & 63) == 0) { red[w] = s; red[4 + w] = sq; }
    __syncthreads();
    s  = red[0] + red[1] + red[2] + red[3];
    sq = red[4] + red[5] + red[6] + red[7];
    float m   = s * (1.f / kD);
    float var = sq * (1.f / kD) - m * m;
    float rs  = rsqrtf(var + kEps);
    float* orow = out + (size_t)r * kD;
    orow[t]       = (x0 - m) * rs * g[t]       + bb[t];
    orow[t + 256] = (x1 - m) * rs * g[t + 256] + bb[t + 256];
    orow[t + 512] = (x2 - m) * rs * g[t + 512] + bb[t + 512];
}

// final LN only over rows t<T, compacted to (B*T, D)
__global__ void k_finalln(const float* __restrict__ h, const float* __restrict__ g,
                          const float* __restrict__ bb, float* __restrict__ out)
{
    int r = blockIdx.x;                 // 0..kB*kT
    int b = r / kT, tt = r % kT;
    const float* xr = h + (size_t)(b * kMC + tt) * kD;
    int t = threadIdx.x;
    float x0 = xr[t], x1 = xr[t + 256], x2 = xr[t + 512];
    float s  = x0 + x1 + x2;
    float sq = x0 * x0 + x1 * x1 + x2 * x2;
    __shared__ float red[8];
    for (int o = 32; o > 0; o >>= 1) { s += __shfl_down(s, o); sq += __shfl_down(sq, o); }
    int w = t >> 6;
    if ((t & 63) == 0) { red[w] = s; red[4 + w] = sq; }
    __syncthreads();
    s  = red[0] + red[1] + red[2] + red[3];
    sq = red[4] + red[5] + red[6] + red[7];
    float m   = s * (1.f / kD);
    float var = sq * (1.f / kD) - m * m;
    float rs  = rsqrtf(var + kEps);
    float* orow = out + (size_t)r * kD;
    orow[t]       = (x0 - m) * rs * g[t]       + bb[t];
    orow[t + 256] = (x1 - m) * rs * g[t + 256] + bb[t + 256];
    orow[t + 512] = (x2 - m) * rs * g[t + 512] + bb[t + 512];
}

// ========================================================================
// Generic fp32 GEMM: out[m,n] = (res?res[m,n]:0) + gelu?( A[m,:]·W[n,:] + bias[n] )
// A: M x K row-major, W: N x K row-major (einsum 'bti,oi->bto' layout).
// 64x64 tile, BK=16, 256 threads, 4x4 microtile/thread.
// ========================================================================
__global__ void gemm_k(const float* __restrict__ A, const float* __restrict__ W,
                       const float* __restrict__ bias, const float* __restrict__ res,
                       float* __restrict__ out, int M, int N, int K, int dogelu)
{
    __shared__ float As[16][68];   // [k][row], padded: rows 16B-aligned, few conflicts
    __shared__ float Bs[16][68];   // [k][col]
    int tid = threadIdx.x;
    int tx = tid & 15, ty = tid >> 4;
    int bn = blockIdx.x * 64, bm = blockIdx.y * 64;
    float acc[4][4] = {};
    for (int k0 = 0; k0 < K; k0 += 16) {
        #pragma unroll
        for (int i = 0; i < 4; ++i) {
            int idx = tid + i * 256;          // 0..1023 -> 64 rows x 16 k
            int r = idx >> 4, kk = idx & 15;
            int gr = bm + r;
            As[kk][r] = (gr < M) ? A[(size_t)gr * K + k0 + kk] : 0.f;
            int gc = bn + r;
            Bs[kk][r] = (gc < N) ? W[(size_t)gc * K + k0 + kk] : 0.f;
        }
        __syncthreads();
        #pragma unroll
        for (int kk = 0; kk < 16; ++kk) {
            float a[4], b[4];
            #pragma unroll
            for (int i = 0; i < 4; ++i) a[i] = As[kk][ty * 4 + i];
            #pragma unroll
            for (int j = 0; j < 4; ++j) b[j] = Bs[kk][tx * 4 + j];
            #pragma unroll
            for (int i = 0; i < 4; ++i)
                #pragma unroll
                for (int j = 0; j < 4; ++j)
                    acc[i][j] += a[i] * b[j];
        }
        __syncthreads();
    }
    #pragma unroll
    for (int i = 0; i < 4; ++i) {
        int m = bm + ty * 4 + i;
        if (m >= M) continue;
        #pragma unroll
        for (int j = 0; j < 4; ++j) {
            int n = bn + tx * 4 + j;
            if (n >= N) continue;
            float v = acc[i][j];
            if (bias) v += bias[n];
            if (dogelu) v = 0.5f * v * (1.f + erff(v * 0.70710678118654752f));
            if (res) v += res[(size_t)m * N + n];
            out[(size_t)m * N + n] = v;
        }
    }
}

// ========================================================================
// Self-attention: one block per (query i, head h, batch b). 256 keys.
// mask: key j valid iff j<=i && j<T.
// ========================================================================
__global__ void k_selfattn(const float* __restrict__ q, const float* __restrict__ kk,
                           const float* __restrict__ vv, float* __restrict__ o)
{
    int i = blockIdx.x, h = blockIdx.y, b = blockIdx.z;
    __shared__ float qs[kDH];
    __shared__ float p[kMC];
    __shared__ float red[8];
    __shared__ float part[4][kDH];
    int t = threadIdx.x;
    if (t < kDH) qs[t] = q[(size_t)(b * kMC + i) * kD + h * kDH + t];
    __syncthreads();
    int j = t;                              // one key per thread
    float sc = -1e30f;
    if (j <= i && j < kT) {
        const float* kr = kk + (size_t)(b * kMC + j) * kD + h * kDH;
        float dot = 0.f;
        #pragma unroll
        for (int d = 0; d < kDH; ++d) dot += qs[d] * kr[d];
        sc = dot * kScale;
    }
    // block max
    float mx = sc;
    for (int off = 32; off > 0; off >>= 1) mx = fmaxf(mx, __shfl_down(mx, off));
    if ((t & 63) == 0) red[t >> 6] = mx;
    __syncthreads();
    mx = fmaxf(fmaxf(red[0], red[1]), fmaxf(red[2], red[3]));
    float e = expf(sc - mx);               // exp(-1e30 - mx) == 0 for masked
    float sm = e;
    for (int off = 32; off > 0; off >>= 1) sm += __shfl_down(sm, off);
    if ((t & 63) == 0) red[4 + (t >> 6)] = sm;
    __syncthreads();
    sm = red[4] + red[5] + red[6] + red[7];
    p[j] = e / sm;
    __syncthreads();
    // PV: threads (group g of 4) x (d of 64)
    int g = t >> 6, d = t & 63;
    const float* vb = vv + (size_t)b * kMC * kD + h * kDH + d;
    float acc = 0.f;
    for (int j2 = g * 64; j2 < g * 64 + 64; ++j2) acc += p[j2] * vb[(size_t)j2 * kD];
    part[g][d] = acc;
    __syncthreads();
    if (t < kDH)
        o[(size_t)(b * kMC + i) * kD + h * kDH + t] =
            part[0][t] + part[1][t] + part[2][t] + part[3][t];
}

// ========================================================================
// Cross-attention: one block per (query i, head h, batch b). 1500 keys, no mask.
// Also writes pre-softmax scaled scores to cqk (rows i<T only).
// ========================================================================
__global__ void k_crossattn(const float* __restrict__ q, const float* __restrict__ ck,
                            const float* __restrict__ cv, float* __restrict__ o,
                            float* __restrict__ cqk)
{
    int i = blockIdx.x, h = blockIdx.y, b = blockIdx.z;
    __shared__ float qs[kDH];
    __shared__ float s[kSA];
    __shared__ float red[8];
    __shared__ float part[4][kDH];
    int t = threadIdx.x;
    if (t < kDH) qs[t] = q[(size_t)(b * kMC + i) * kD + h * kDH + t];
    __syncthreads();
    float lmax = -1e30f;
    for (int j = t; j < kSA; j += 256) {
        const float* kr = ck + (size_t)j * kD + h * kDH;
        float dot = 0.f;
        #pragma unroll
        for (int d = 0; d < kDH; ++d) dot += qs[d] * kr[d];
        dot *= kScale;
        s[j] = dot;
        if (i < kT)
            cqk[((size_t)(b * kH + h) * kT + i) * kSA + j] = dot;
        lmax = fmaxf(lmax, dot);
    }
    for (int off = 32; off > 0; off >>= 1) lmax = fmaxf(lmax, __shfl_down(lmax, off));
    if ((t & 63) == 0) red[t >> 6] = lmax;
    __syncthreads();
    float mx = fmaxf(fmaxf(red[0], red[1]), fmaxf(red[2], red[3]));
    float lsum = 0.f;
    for (int j = t; j < kSA; j += 256) {
        float e = expf(s[j] - mx);
        s[j] = e;
        lsum += e;
    }
    for (int off = 32; off > 0; off >>= 1) lsum += __shfl_down(lsum, off);
    if ((t & 63) == 0) red[4 + (t >> 6)] = lsum;
    __syncthreads();
    float inv = 1.f / (red[4] + red[5] + red[6] + red[7]);
    // PV: 4 groups x 375 keys each
    int g = t >> 6, d = t & 63;
    const float* vb = cv + h * kDH + d;
    float acc = 0.f;
    for (int j2 = g * 375; j2 < g * 375 + 375; ++j2) acc += s[j2] * vb[(size_t)j2 * kD];
    part[g][d] = acc;
    __syncthreads();
    if (t < kDH)
        o[(size_t)(b * kMC + i) * kD + h * kDH + t] =
            (part[0][t] + part[1][t] + part[2][t] + part[3][t]) * inv;
}

// ========================================================================
extern "C" void kernel_launch(void* const* d_in, const int* in_sizes, int n_in,
                              void* d_out, int out_size, void* d_ws, size_t ws_size,
                              hipStream_t stream)
{
    const int*   x   = (const int*)  d_in[0];
    const float* xa  = (const float*)d_in[1];   // use only xa[:1] -> first 1500*768
    const float* tok = (const float*)d_in[4];
    const float* pos = (const float*)d_in[5];
    const float* attn_ln_g  = (const float*)d_in[6];
    const float* attn_ln_b  = (const float*)d_in[7];
    const float* attn_q_w   = (const float*)d_in[8];
    const float* attn_q_b   = (const float*)d_in[9];
    const float* attn_k_w   = (const float*)d_in[10];
    const float* attn_v_w   = (const float*)d_in[11];
    const float* attn_v_b   = (const float*)d_in[12];
    const float* attn_o_w   = (const float*)d_in[13];
    const float* attn_o_b   = (const float*)d_in[14];
    const float* cross_ln_g = (const float*)d_in[15];
    const float* cross_ln_b = (const float*)d_in[16];
    const float* cross_q_w  = (const float*)d_in[17];
    const float* cross_q_b  = (const float*)d_in[18];
    const float* cross_k_w  = (const float*)d_in[19];
    const float* cross_v_w  = (const float*)d_in[20];
    const float* cross_v_b  = (const float*)d_in[21];
    const float* cross_o_w  = (const float*)d_in[22];
    const float* cross_o_b  = (const float*)d_in[23];
    const float* mlp_ln_g   = (const float*)d_in[24];
    const float* mlp_ln_b   = (const float*)d_in[25];
    const float* mlp_w1     = (const float*)d_in[26];
    const float* mlp_b1     = (const float*)d_in[27];
    const float* mlp_w2     = (const float*)d_in[28];
    const float* mlp_b2     = (const float*)d_in[29];
    const float* ln_g       = (const float*)d_in[30];
    const float* ln_b       = (const float*)d_in[31];

    float* out = (float*)d_out;
    // workspace: h, y, q, o (each R*D), hid (R*4D), yF (B*T*D)  ~13.8 MB
    float* h   = (float*)d_ws;
    float* y   = h   + (size_t)kR * kD;
    float* q   = y   + (size_t)kR * kD;
    float* o   = q   + (size_t)kR * kD;
    float* hid = o   + (size_t)kR * kD;
    float* yF  = hid + (size_t)kR * 4 * kD;

    auto gemm = [&](const float* A, const float* W, const float* bias, const float* res,
                    float* O, int M, int N, int K, int dogelu) {
        dim3 grid((N + 63) / 64, (M + 63) / 64);
        gemm_k<<<grid, 256, 0, stream>>>(A, W, bias, res, O, M, N, K, dogelu);
    };

    k_embed<<<kB * kMC * kD / 256, 256, 0, stream>>>(x, tok, pos, h);

    for (int l = 0; l < kL; ++l) {
        size_t dd  = (size_t)l * kD * kD;
        float* kbuf  = out + OFF_MKV + (size_t)(2 * l)     * kB * kMC * kD;
        float* vbuf  = out + OFF_MKV + (size_t)(2 * l + 1) * kB * kMC * kD;
        float* ckbuf = out + OFF_CKV + (size_t)(2 * l)     * kSA * kD;
        float* cvbuf = out + OFF_CKV + (size_t)(2 * l + 1) * kSA * kD;
        float* cqk   = out + OFF_CQK + (size_t)l * kB * kH * kT * kSA;

        // --- self attention ---
        k_ln<<<kR, 256, 0, stream>>>(h, attn_ln_g + l * kD, attn_ln_b + l * kD, y);
        gemm(y, attn_q_w + dd, attn_q_b + l * kD, nullptr, q,    kR, kD, kD, 0);
        gemm(y, attn_k_w + dd, nullptr,           nullptr, kbuf, kR, kD, kD, 0);
        gemm(y, attn_v_w + dd, attn_v_b + l * kD, nullptr, vbuf, kR, kD, kD, 0);
        k_selfattn<<<dim3(kMC, kH, kB), 256, 0, stream>>>(q, kbuf, vbuf, o);
        gemm(o, attn_o_w + dd, attn_o_b + l * kD, h, h, kR, kD, kD, 0);

        // --- cross attention ---
        k_ln<<<kR, 256, 0, stream>>>(h, cross_ln_g + l * kD, cross_ln_b + l * kD, y);
        gemm(y,  cross_q_w + dd, cross_q_b + l * kD, nullptr, q,     kR,  kD, kD, 0);
        gemm(xa, cross_k_w + dd, nullptr,            nullptr, ckbuf, kSA, kD, kD, 0);
        gemm(xa, cross_v_w + dd, cross_v_b + l * kD, nullptr, cvbuf, kSA, kD, kD, 0);
        k_crossattn<<<dim3(kMC, kH, kB), 256, 0, stream>>>(q, ckbuf, cvbuf, o, cqk);
        gemm(o, cross_o_w + dd, cross_o_b + l * kD, h, h, kR, kD, kD, 0);

        // --- MLP ---
        k_ln<<<kR, 256, 0, stream>>>(h, mlp_ln_g + l * kD, mlp_ln_b + l * kD, y);
        gemm(y,   mlp_w1 + (size_t)l * 4 * kD * kD, mlp_b1 + (size_t)l * 4 * kD,
             nullptr, hid, kR, 4 * kD, kD, 1);
        gemm(hid, mlp_w2 + (size_t)l * 4 * kD * kD, mlp_b2 + l * kD,
             h, h, kR, kD, 4 * kD, 0);
    }

    k_finalln<<<kB * kT, 256, 0, stream>>>(h, ln_g, ln_b, yF);
    gemm(yF, tok, nullptr, nullptr, out, kB * kT, kV, kD, 0);
}

// Round 2
// 10209.378 us; speedup vs baseline: 2.2838x; 2.2838x over previous
//
#include <hip/hip_runtime.h>
#include <math.h>

// ---- problem constants --------------------------------------------------
constexpr int kL = 12, kD = 768, kH = 12, kV = 51865, kSA = 1500;
constexpr int kB = 2, kT = 192, kMC = 256, kDH = 64;
constexpr float kScale = 0.125f;      // DH^-0.5
constexpr float kEps = 1e-5f;
constexpr int kR = kB * kMC;          // 512 rows through the layer stack

// ---- d_out layout (flat float32, reference return order) ---------------
constexpr size_t SZ_LOGITS = (size_t)kB * kT * kV;
constexpr size_t SZ_CQK    = (size_t)kL * kB * kH * kT * kSA;
constexpr size_t SZ_MKV    = (size_t)2 * kL * kB * kMC * kD;
constexpr size_t OFF_CQK = SZ_LOGITS;
constexpr size_t OFF_MKV = OFF_CQK + SZ_CQK;
constexpr size_t OFF_CKV = OFF_MKV + SZ_MKV;

typedef float f32x4v __attribute__((ext_vector_type(4)));
typedef unsigned short us8v __attribute__((ext_vector_type(8)));
typedef unsigned short us4v __attribute__((ext_vector_type(4)));

static __device__ __forceinline__ unsigned short f2bf(float f) {
    unsigned int u = __float_as_uint(f);
    u += 0x7fffu + ((u >> 16) & 1u);          // round-to-nearest-even
    return (unsigned short)(u >> 16);
}

static __device__ __forceinline__ f32x4v mfma_bf16(us8v a, us8v b, f32x4v c) {
    asm("v_mfma_f32_16x16x32_bf16 %0, %1, %2, %0" : "+v"(c) : "v"(a), "v"(b));
    return c;
}

// ========================================================================
// embedding
// ========================================================================
__global__ void k_embed(const int* __restrict__ x, const float* __restrict__ tok,
                        const float* __restrict__ pos, float* __restrict__ h)
{
    int idx = blockIdx.x * 256 + threadIdx.x;
    int d = idx % kD;
    int t = (idx / kD) % kMC;
    int b = idx / (kD * kMC);
    float v = 0.f;
    if (t < kT) {
        int tokid = x[b * kT + t];
        v = tok[(size_t)tokid * kD + d] + pos[(size_t)t * kD + d];
    }
    h[idx] = v;
}

// ========================================================================
// LayerNorm (256 thr per row of 768)
// ========================================================================
__global__ void k_ln(const float* __restrict__ in, const float* __restrict__ g,
                     const float* __restrict__ bb, float* __restrict__ out)
{
    int r = blockIdx.x;
    const float* xr = in + (size_t)r * kD;
    int t = threadIdx.x;
    float x0 = xr[t], x1 = xr[t + 256], x2 = xr[t + 512];
    float s  = x0 + x1 + x2;
    float sq = x0 * x0 + x1 * x1 + x2 * x2;
    __shared__ float red[8];
    for (int o = 32; o > 0; o >>= 1) { s += __shfl_down(s, o); sq += __shfl_down(sq, o); }
    int w = t >> 6;
    if ((t & 63) == 0) { red[w] = s; red[4 + w] = sq; }
    __syncthreads();
    s  = red[0] + red[1] + red[2] + red[3];
    sq = red[4] + red[5] + red[6] + red[7];
    float m   = s * (1.f / kD);
    float var = sq * (1.f / kD) - m * m;
    float rs  = rsqrtf(var + kEps);
    float* orow = out + (size_t)r * kD;
    orow[t]       = (x0 - m) * rs * g[t]       + bb[t];
    orow[t + 256] = (x1 - m) * rs * g[t + 256] + bb[t + 256];
    orow[t + 512] = (x2 - m) * rs * g[t + 512] + bb[t + 512];
}

__global__ void k_finalln(const float* __restrict__ h, const float* __restrict__ g,
                          const float* __restrict__ bb, float* __restrict__ out)
{
    int r = blockIdx.x;                 // 0..kB*kT
    int b = r / kT, tt = r % kT;
    const float* xr = h + (size_t)(b * kMC + tt) * kD;
    int t = threadIdx.x;
    float x0 = xr[t], x1 = xr[t + 256], x2 = xr[t + 512];
    float s  = x0 + x1 + x2;
    float sq = x0 * x0 + x1 * x1 + x2 * x2;
    __shared__ float red[8];
    for (int o = 32; o > 0; o >>= 1) { s += __shfl_down(s, o); sq += __shfl_down(sq, o); }
    int w = t >> 6;
    if ((t & 63) == 0) { red[w] = s; red[4 + w] = sq; }
    __syncthreads();
    s  = red[0] + red[1] + red[2] + red[3];
    sq = red[4] + red[5] + red[6] + red[7];
    float m   = s * (1.f / kD);
    float var = sq * (1.f / kD) - m * m;
    float rs  = rsqrtf(var + kEps);
    float* orow = out + (size_t)r * kD;
    orow[t]       = (x0 - m) * rs * g[t]       + bb[t];
    orow[t + 256] = (x1 - m) * rs * g[t + 256] + bb[t + 256];
    orow[t + 512] = (x2 - m) * rs * g[t + 512] + bb[t + 512];
}

// ========================================================================
// bf16-MFMA GEMM, z-batched via pointer table.
// out[m,n] = (res? res[m,n]:0) + act( A[m,:]·W[n,:] + bias[n] )
// A: M x K fp32 row-major, W: N x K fp32 row-major. BM=BN=64, BK=32.
// 256 thr = 4 waves (2x2), each wave 32x32 = 2x2 fragments of 16x16x32.
// ========================================================================
struct GEntry { const float* W; const float* bias; const float* res; float* out; };
struct GBatch { GEntry e[24]; };

__global__ __launch_bounds__(256)
void gemm_mfma(const float* __restrict__ A, GBatch gb,
               int M, int N, int K, int dogelu)
{
    constexpr int LDT = 40;                       // bf16 row stride (pad 8)
    __shared__ unsigned short As[64][LDT];
    __shared__ unsigned short Ws[64][LDT];
    const GEntry ge = gb.e[blockIdx.z];
    const float* __restrict__ W = ge.W;
    int bm = blockIdx.x * 64;
    int bn = blockIdx.y * 64;
    int tid = threadIdx.x;
    int wid = tid >> 6, lane = tid & 63;
    int wm = (wid >> 1) * 32, wn = (wid & 1) * 32;
    int l15 = lane & 15, lg = lane >> 4;

    f32x4v acc00 = {}, acc01 = {}, acc10 = {}, acc11 = {};

    for (int k0 = 0; k0 < K; k0 += 32) {
        #pragma unroll
        for (int i = 0; i < 2; ++i) {
            int id = tid + i * 256;               // 0..511
            int r = id >> 3, kq = (id & 7) * 4;
            int gr = bm + r;
            float4 va = make_float4(0.f, 0.f, 0.f, 0.f);
            if (gr < M) va = *(const float4*)(A + (size_t)gr * K + k0 + kq);
            us4v pa;
            pa[0] = f2bf(va.x); pa[1] = f2bf(va.y); pa[2] = f2bf(va.z); pa[3] = f2bf(va.w);
            *(us4v*)&As[r][kq] = pa;
            int gc = bn + r;
            float4 vw = make_float4(0.f, 0.f, 0.f, 0.f);
            if (gc < N) vw = *(const float4*)(W + (size_t)gc * K + k0 + kq);
            us4v pw;
            pw[0] = f2bf(vw.x); pw[1] = f2bf(vw.y); pw[2] = f2bf(vw.z); pw[3] = f2bf(vw.w);
            *(us4v*)&Ws[r][kq] = pw;
        }
        __syncthreads();
        us8v af0 = *(const us8v*)&As[wm + l15][lg * 8];
        us8v af1 = *(const us8v*)&As[wm + 16 + l15][lg * 8];
        us8v wf0 = *(const us8v*)&Ws[wn + l15][lg * 8];
        us8v wf1 = *(const us8v*)&Ws[wn + 16 + l15][lg * 8];
        acc00 = mfma_bf16(af0, wf0, acc00);
        acc01 = mfma_bf16(af0, wf1, acc01);
        acc10 = mfma_bf16(af1, wf0, acc10);
        acc11 = mfma_bf16(af1, wf1, acc11);
        __syncthreads();
    }

    const float* bias = ge.bias;
    const float* res  = ge.res;
    float* outp = ge.out;
    f32x4v accs[2][2] = { { acc00, acc01 }, { acc10, acc11 } };
    #pragma unroll
    for (int fi = 0; fi < 2; ++fi) {
        #pragma unroll
        for (int fj = 0; fj < 2; ++fj) {
            int col = bn + wn + fj * 16 + l15;
            if (col >= N) continue;
            float bv = bias ? bias[col] : 0.f;
            #pragma unroll
            for (int r = 0; r < 4; ++r) {
                int row = bm + wm + fi * 16 + lg * 4 + r;
                if (row >= M) continue;
                float v = accs[fi][fj][r] + bv;
                if (dogelu) v = 0.5f * v * (1.f + erff(v * 0.70710678118654752f));
                if (res) v += res[(size_t)row * N + col];
                outp[(size_t)row * N + col] = v;
            }
        }
    }
}

// ========================================================================
// Self-attention: one block per (query i, head h, batch b). 256 keys.
// ========================================================================
__global__ void k_selfattn(const float* __restrict__ q, const float* __restrict__ kk,
                           const float* __restrict__ vv, float* __restrict__ o)
{
    int i = blockIdx.x, h = blockIdx.y, b = blockIdx.z;
    __shared__ float qs[kDH];
    __shared__ float p[kMC];
    __shared__ float red[8];
    __shared__ float part[4][kDH];
    int t = threadIdx.x;
    if (t < kDH) qs[t] = q[(size_t)(b * kMC + i) * kD + h * kDH + t];
    __syncthreads();
    int j = t;
    float sc = -1e30f;
    if (j <= i && j < kT) {
        const float* kr = kk + (size_t)(b * kMC + j) * kD + h * kDH;
        float dot = 0.f;
        #pragma unroll
        for (int d = 0; d < kDH; ++d) dot += qs[d] * kr[d];
        sc = dot * kScale;
    }
    float mx = sc;
    for (int off = 32; off > 0; off >>= 1) mx = fmaxf(mx, __shfl_down(mx, off));
    if ((t & 63) == 0) red[t >> 6] = mx;
    __syncthreads();
    mx = fmaxf(fmaxf(red[0], red[1]), fmaxf(red[2], red[3]));
    float e = expf(sc - mx);
    float sm = e;
    for (int off = 32; off > 0; off >>= 1) sm += __shfl_down(sm, off);
    if ((t & 63) == 0) red[4 + (t >> 6)] = sm;
    __syncthreads();
    sm = red[4] + red[5] + red[6] + red[7];
    p[j] = e / sm;
    __syncthreads();
    int g = t >> 6, d = t & 63;
    const float* vb = vv + (size_t)b * kMC * kD + h * kDH + d;
    float acc = 0.f;
    for (int j2 = g * 64; j2 < g * 64 + 64; ++j2) acc += p[j2] * vb[(size_t)j2 * kD];
    part[g][d] = acc;
    __syncthreads();
    if (t < kDH)
        o[(size_t)(b * kMC + i) * kD + h * kDH + t] =
            part[0][t] + part[1][t] + part[2][t] + part[3][t];
}

// ========================================================================
// Cross-attention, 8 queries per block. grid (kMC/8, H, B), 256 thr.
// ========================================================================
__global__ __launch_bounds__(256)
void k_crossattn8(const float* __restrict__ q, const float* __restrict__ ck,
                  const float* __restrict__ cv, float* __restrict__ o,
                  float* __restrict__ cqk)
{
    int qt = blockIdx.x * 8, h = blockIdx.y, b = blockIdx.z;
    __shared__ float qs[8][kDH];
    __shared__ float s[8][kSA];
    __shared__ float rinv[8];
    int t = threadIdx.x;
    for (int idx = t; idx < 8 * kDH; idx += 256)
        qs[idx >> 6][idx & 63] =
            q[(size_t)(b * kMC + qt + (idx >> 6)) * kD + h * kDH + (idx & 63)];
    __syncthreads();
    // scores: thread handles key rows j, j+256, ... ; 8 dots each via float4
    for (int j = t; j < kSA; j += 256) {
        const float4* kr = (const float4*)(ck + (size_t)j * kD + h * kDH);
        float dq[8] = {};
        #pragma unroll
        for (int d4 = 0; d4 < 16; ++d4) {
            float4 kv = kr[d4];
            #pragma unroll
            for (int qq = 0; qq < 8; ++qq) {
                float4 qv = *(const float4*)&qs[qq][d4 * 4];
                dq[qq] += kv.x * qv.x + kv.y * qv.y + kv.z * qv.z + kv.w * qv.w;
            }
        }
        #pragma unroll
        for (int qq = 0; qq < 8; ++qq) {
            float sc = dq[qq] * kScale;
            s[qq][j] = sc;
            if (qt + qq < kT)
                cqk[((size_t)(b * kH + h) * kT + qt + qq) * kSA + j] = sc;
        }
    }
    __syncthreads();
    // softmax: wave w handles rows w and w+4
    int wv = t >> 6, ln = t & 63;
    for (int r = wv; r < 8; r += 4) {
        float mx = -1e30f;
        for (int j = ln; j < kSA; j += 64) mx = fmaxf(mx, s[r][j]);
        for (int off = 32; off > 0; off >>= 1) mx = fmaxf(mx, __shfl_xor(mx, off));
        float sum = 0.f;
        for (int j = ln; j < kSA; j += 64) {
            float e = expf(s[r][j] - mx);
            s[r][j] = e;
            sum += e;
        }
        for (int off = 32; off > 0; off >>= 1) sum += __shfl_xor(sum, off);
        if (ln == 0) rinv[r] = 1.f / sum;
    }
    __syncthreads();
    // PV: thread -> (qq = t>>5, d0 = (t&31)*2)
    int qq = t >> 5, d0 = (t & 31) * 2;
    const float* vb = cv + h * kDH + d0;
    float a0 = 0.f, a1 = 0.f, c0 = 0.f, c1 = 0.f;
    for (int j = 0; j < kSA; j += 2) {
        float p0 = s[qq][j], p1 = s[qq][j + 1];
        float2 v0 = *(const float2*)(vb + (size_t)j * kD);
        float2 v1 = *(const float2*)(vb + (size_t)(j + 1) * kD);
        a0 += p0 * v0.x; a1 += p0 * v0.y;
        c0 += p1 * v1.x; c1 += p1 * v1.y;
    }
    float inv = rinv[qq];
    float* orow = o + (size_t)(b * kMC + qt + qq) * kD + h * kDH + d0;
    orow[0] = (a0 + c0) * inv;
    orow[1] = (a1 + c1) * inv;
}

// ========================================================================
extern "C" void kernel_launch(void* const* d_in, const int* in_sizes, int n_in,
                              void* d_out, int out_size, void* d_ws, size_t ws_size,
                              hipStream_t stream)
{
    const int*   x   = (const int*)  d_in[0];
    const float* xa  = (const float*)d_in[1];
    const float* tok = (const float*)d_in[4];
    const float* pos = (const float*)d_in[5];
    const float* attn_ln_g  = (const float*)d_in[6];
    const float* attn_ln_b  = (const float*)d_in[7];
    const float* attn_q_w   = (const float*)d_in[8];
    const float* attn_q_b   = (const float*)d_in[9];
    const float* attn_k_w   = (const float*)d_in[10];
    const float* attn_v_w   = (const float*)d_in[11];
    const float* attn_v_b   = (const float*)d_in[12];
    const float* attn_o_w   = (const float*)d_in[13];
    const float* attn_o_b   = (const float*)d_in[14];
    const float* cross_ln_g = (const float*)d_in[15];
    const float* cross_ln_b = (const float*)d_in[16];
    const float* cross_q_w  = (const float*)d_in[17];
    const float* cross_q_b  = (const float*)d_in[18];
    const float* cross_k_w  = (const float*)d_in[19];
    const float* cross_v_w  = (const float*)d_in[20];
    const float* cross_v_b  = (const float*)d_in[21];
    const float* cross_o_w  = (const float*)d_in[22];
    const float* cross_o_b  = (const float*)d_in[23];
    const float* mlp_ln_g   = (const float*)d_in[24];
    const float* mlp_ln_b   = (const float*)d_in[25];
    const float* mlp_w1     = (const float*)d_in[26];
    const float* mlp_b1     = (const float*)d_in[27];
    const float* mlp_w2     = (const float*)d_in[28];
    const float* mlp_b2     = (const float*)d_in[29];
    const float* ln_g       = (const float*)d_in[30];
    const float* ln_b       = (const float*)d_in[31];

    float* out = (float*)d_out;
    float* h   = (float*)d_ws;
    float* y   = h   + (size_t)kR * kD;
    float* qws = y   + (size_t)kR * kD;
    float* o   = qws + (size_t)kR * kD;
    float* hid = o   + (size_t)kR * kD;
    float* yF  = hid + (size_t)kR * 4 * kD;

    auto gemm1 = [&](const float* A, const float* W, const float* bias, const float* res,
                     float* O, int M, int N, int K, int dogelu) {
        GBatch g{};
        g.e[0] = { W, bias, res, O };
        gemm_mfma<<<dim3((M + 63) / 64, (N + 63) / 64, 1), 256, 0, stream>>>(
            A, g, M, N, K, dogelu);
    };

    k_embed<<<kB * kMC * kD / 256, 256, 0, stream>>>(x, tok, pos, h);

    // all cross K/V projections (layer-invariant input xa) in ONE launch
    {
        GBatch gc{};
        for (int l = 0; l < kL; ++l) {
            gc.e[2 * l]     = { cross_k_w + (size_t)l * kD * kD, nullptr, nullptr,
                                out + OFF_CKV + (size_t)(2 * l) * kSA * kD };
            gc.e[2 * l + 1] = { cross_v_w + (size_t)l * kD * kD, cross_v_b + (size_t)l * kD,
                                nullptr,
                                out + OFF_CKV + (size_t)(2 * l + 1) * kSA * kD };
        }
        gemm_mfma<<<dim3((kSA + 63) / 64, kD / 64, 2 * kL), 256, 0, stream>>>(
            xa, gc, kSA, kD, kD, 0);
    }

    for (int l = 0; l < kL; ++l) {
        size_t dd = (size_t)l * kD * kD;
        float* kbuf  = out + OFF_MKV + (size_t)(2 * l)     * kB * kMC * kD;
        float* vbuf  = out + OFF_MKV + (size_t)(2 * l + 1) * kB * kMC * kD;
        float* ckbuf = out + OFF_CKV + (size_t)(2 * l)     * kSA * kD;
        float* cvbuf = out + OFF_CKV + (size_t)(2 * l + 1) * kSA * kD;
        float* cqk   = out + OFF_CQK + (size_t)l * kB * kH * kT * kSA;

        // --- self attention ---
        k_ln<<<kR, 256, 0, stream>>>(h, attn_ln_g + l * kD, attn_ln_b + l * kD, y);
        {
            GBatch g3{};
            g3.e[0] = { attn_q_w + dd, attn_q_b + (size_t)l * kD, nullptr, qws };
            g3.e[1] = { attn_k_w + dd, nullptr,                   nullptr, kbuf };
            g3.e[2] = { attn_v_w + dd, attn_v_b + (size_t)l * kD, nullptr, vbuf };
            gemm_mfma<<<dim3(kR / 64, kD / 64, 3), 256, 0, stream>>>(y, g3, kR, kD, kD, 0);
        }
        k_selfattn<<<dim3(kMC, kH, kB), 256, 0, stream>>>(qws, kbuf, vbuf, o);
        gemm1(o, attn_o_w + dd, attn_o_b + l * kD, h, h, kR, kD, kD, 0);

        // --- cross attention ---
        k_ln<<<kR, 256, 0, stream>>>(h, cross_ln_g + l * kD, cross_ln_b + l * kD, y);
        gemm1(y, cross_q_w + dd, cross_q_b + l * kD, nullptr, qws, kR, kD, kD, 0);
        k_crossattn8<<<dim3(kMC / 8, kH, kB), 256, 0, stream>>>(qws, ckbuf, cvbuf, o, cqk);
        gemm1(o, cross_o_w + dd, cross_o_b + l * kD, h, h, kR, kD, kD, 0);

        // --- MLP ---
        k_ln<<<kR, 256, 0, stream>>>(h, mlp_ln_g + l * kD, mlp_ln_b + l * kD, y);
        gemm1(y,   mlp_w1 + (size_t)l * 4 * kD * kD, mlp_b1 + (size_t)l * 4 * kD,
              nullptr, hid, kR, 4 * kD, kD, 1);
        gemm1(hid, mlp_w2 + (size_t)l * 4 * kD * kD, mlp_b2 + l * kD,
              h, h, kR, kD, 4 * kD, 0);
    }

    k_finalln<<<kB * kT, 256, 0, stream>>>(h, ln_g, ln_b, yF);
    gemm1(yF, tok, nullptr, nullptr, out, kB * kT, kV, kD, 0);
}

// Round 3
// 7379.842 us; speedup vs baseline: 3.1595x; 1.3834x over previous
//
#include <hip/hip_runtime.h>
#include <math.h>

// ---- problem constants --------------------------------------------------
constexpr int kL = 12, kD = 768, kH = 12, kV = 51865, kSA = 1500;
constexpr int kB = 2, kT = 192, kMC = 256, kDH = 64;
constexpr float kScale = 0.125f;      // DH^-0.5
constexpr float kEps = 1e-5f;
constexpr int kR = kB * kMC;          // 512 rows through the layer stack
constexpr int kSLDc = 1504;           // cross score row stride (pad)

// ---- d_out layout (flat float32, reference return order) ---------------
constexpr size_t SZ_LOGITS = (size_t)kB * kT * kV;
constexpr size_t SZ_CQK    = (size_t)kL * kB * kH * kT * kSA;
constexpr size_t SZ_MKV    = (size_t)2 * kL * kB * kMC * kD;
constexpr size_t OFF_CQK = SZ_LOGITS;
constexpr size_t OFF_MKV = OFF_CQK + SZ_CQK;
constexpr size_t OFF_CKV = OFF_MKV + SZ_MKV;

typedef float f32x4v __attribute__((ext_vector_type(4)));
typedef unsigned short us8v __attribute__((ext_vector_type(8)));
typedef unsigned short us4v __attribute__((ext_vector_type(4)));

static __device__ __forceinline__ unsigned short f2bf(float f) {
    unsigned int u = __float_as_uint(f);
    u += 0x7fffu + ((u >> 16) & 1u);          // round-to-nearest-even
    return (unsigned short)(u >> 16);
}

static __device__ __forceinline__ f32x4v mfma_bf16(us8v a, us8v b, f32x4v c) {
    asm("v_mfma_f32_16x16x32_bf16 %0, %1, %2, %0" : "+v"(c) : "v"(a), "v"(b));
    return c;
}

// ========================================================================
// embedding
// ========================================================================
__global__ void k_embed(const int* __restrict__ x, const float* __restrict__ tok,
                        const float* __restrict__ pos, float* __restrict__ h)
{
    int idx = blockIdx.x * 256 + threadIdx.x;
    int d = idx % kD;
    int t = (idx / kD) % kMC;
    int b = idx / (kD * kMC);
    float v = 0.f;
    if (t < kT) {
        int tokid = x[b * kT + t];
        v = tok[(size_t)tokid * kD + d] + pos[(size_t)t * kD + d];
    }
    h[idx] = v;
}

// ========================================================================
// LayerNorm (256 thr per row of 768)
// ========================================================================
__global__ void k_ln(const float* __restrict__ in, const float* __restrict__ g,
                     const float* __restrict__ bb, float* __restrict__ out)
{
    int r = blockIdx.x;
    const float* xr = in + (size_t)r * kD;
    int t = threadIdx.x;
    float x0 = xr[t], x1 = xr[t + 256], x2 = xr[t + 512];
    float s  = x0 + x1 + x2;
    float sq = x0 * x0 + x1 * x1 + x2 * x2;
    __shared__ float red[8];
    for (int o = 32; o > 0; o >>= 1) { s += __shfl_down(s, o); sq += __shfl_down(sq, o); }
    int w = t >> 6;
    if ((t & 63) == 0) { red[w] = s; red[4 + w] = sq; }
    __syncthreads();
    s  = red[0] + red[1] + red[2] + red[3];
    sq = red[4] + red[5] + red[6] + red[7];
    float m   = s * (1.f / kD);
    float var = sq * (1.f / kD) - m * m;
    float rs  = rsqrtf(var + kEps);
    float* orow = out + (size_t)r * kD;
    orow[t]       = (x0 - m) * rs * g[t]       + bb[t];
    orow[t + 256] = (x1 - m) * rs * g[t + 256] + bb[t + 256];
    orow[t + 512] = (x2 - m) * rs * g[t + 512] + bb[t + 512];
}

__global__ void k_finalln(const float* __restrict__ h, const float* __restrict__ g,
                          const float* __restrict__ bb, float* __restrict__ out)
{
    int r = blockIdx.x;                 // 0..kB*kT
    int b = r / kT, tt = r % kT;
    const float* xr = h + (size_t)(b * kMC + tt) * kD;
    int t = threadIdx.x;
    float x0 = xr[t], x1 = xr[t + 256], x2 = xr[t + 512];
    float s  = x0 + x1 + x2;
    float sq = x0 * x0 + x1 * x1 + x2 * x2;
    __shared__ float red[8];
    for (int o = 32; o > 0; o >>= 1) { s += __shfl_down(s, o); sq += __shfl_down(sq, o); }
    int w = t >> 6;
    if ((t & 63) == 0) { red[w] = s; red[4 + w] = sq; }
    __syncthreads();
    s  = red[0] + red[1] + red[2] + red[3];
    sq = red[4] + red[5] + red[6] + red[7];
    float m   = s * (1.f / kD);
    float var = sq * (1.f / kD) - m * m;
    float rs  = rsqrtf(var + kEps);
    float* orow = out + (size_t)r * kD;
    orow[t]       = (x0 - m) * rs * g[t]       + bb[t];
    orow[t + 256] = (x1 - m) * rs * g[t + 256] + bb[t + 256];
    orow[t + 512] = (x2 - m) * rs * g[t + 512] + bb[t + 512];
}

// ========================================================================
// bf16-MFMA GEMM, z-batched via pointer table (unchanged from round 2)
// ========================================================================
struct GEntry { const float* W; const float* bias; const float* res; float* out; };
struct GBatch { GEntry e[24]; };

__global__ __launch_bounds__(256)
void gemm_mfma(const float* __restrict__ A, GBatch gb,
               int M, int N, int K, int dogelu)
{
    constexpr int LDT = 40;                       // bf16 row stride (pad 8)
    __shared__ unsigned short As[64][LDT];
    __shared__ unsigned short Ws[64][LDT];
    const GEntry ge = gb.e[blockIdx.z];
    const float* __restrict__ W = ge.W;
    int bm = blockIdx.x * 64;
    int bn = blockIdx.y * 64;
    int tid = threadIdx.x;
    int wid = tid >> 6, lane = tid & 63;
    int wm = (wid >> 1) * 32, wn = (wid & 1) * 32;
    int l15 = lane & 15, lg = lane >> 4;

    f32x4v acc00 = {}, acc01 = {}, acc10 = {}, acc11 = {};

    for (int k0 = 0; k0 < K; k0 += 32) {
        #pragma unroll
        for (int i = 0; i < 2; ++i) {
            int id = tid + i * 256;               // 0..511
            int r = id >> 3, kq = (id & 7) * 4;
            int gr = bm + r;
            float4 va = make_float4(0.f, 0.f, 0.f, 0.f);
            if (gr < M) va = *(const float4*)(A + (size_t)gr * K + k0 + kq);
            us4v pa;
            pa[0] = f2bf(va.x); pa[1] = f2bf(va.y); pa[2] = f2bf(va.z); pa[3] = f2bf(va.w);
            *(us4v*)&As[r][kq] = pa;
            int gc = bn + r;
            float4 vw = make_float4(0.f, 0.f, 0.f, 0.f);
            if (gc < N) vw = *(const float4*)(W + (size_t)gc * K + k0 + kq);
            us4v pw;
            pw[0] = f2bf(vw.x); pw[1] = f2bf(vw.y); pw[2] = f2bf(vw.z); pw[3] = f2bf(vw.w);
            *(us4v*)&Ws[r][kq] = pw;
        }
        __syncthreads();
        us8v af0 = *(const us8v*)&As[wm + l15][lg * 8];
        us8v af1 = *(const us8v*)&As[wm + 16 + l15][lg * 8];
        us8v wf0 = *(const us8v*)&Ws[wn + l15][lg * 8];
        us8v wf1 = *(const us8v*)&Ws[wn + 16 + l15][lg * 8];
        acc00 = mfma_bf16(af0, wf0, acc00);
        acc01 = mfma_bf16(af0, wf1, acc01);
        acc10 = mfma_bf16(af1, wf0, acc10);
        acc11 = mfma_bf16(af1, wf1, acc11);
        __syncthreads();
    }

    const float* bias = ge.bias;
    const float* res  = ge.res;
    float* outp = ge.out;
    f32x4v accs[2][2] = { { acc00, acc01 }, { acc10, acc11 } };
    #pragma unroll
    for (int fi = 0; fi < 2; ++fi) {
        #pragma unroll
        for (int fj = 0; fj < 2; ++fj) {
            int col = bn + wn + fj * 16 + l15;
            if (col >= N) continue;
            float bv = bias ? bias[col] : 0.f;
            #pragma unroll
            for (int r = 0; r < 4; ++r) {
                int row = bm + wm + fi * 16 + lg * 4 + r;
                if (row >= M) continue;
                float v = accs[fi][fj][r] + bv;
                if (dogelu) v = 0.5f * v * (1.f + erff(v * 0.70710678118654752f));
                if (res) v += res[(size_t)row * N + col];
                outp[(size_t)row * N + col] = v;
            }
        }
    }
}

// ========================================================================
// Attention scores via MFMA: S[z][i][j] = scale * Q[i,:]·K[j,:]  (z = b*12+h)
// 64x64 tile per block, K-dim = 64 (head dim). Writes fp32 scratch (+mask
// for self), and mirrors cross scores into cqk output for rows i < kT.
// ========================================================================
__global__ __launch_bounds__(256)
void k_scores(const float* __restrict__ q, const float* __restrict__ kk,
              float* __restrict__ sws, float* __restrict__ cqk,
              int Nk, int sld, int selfmask, int kPerB)
{
    constexpr int LD = 72;                        // bf16 row stride (pad 8)
    __shared__ unsigned short As[64][LD];
    __shared__ unsigned short Ks[64][LD];
    int z = blockIdx.z, b = z / kH, h = z % kH;
    int bm = blockIdx.x * 64, bn = blockIdx.y * 64;
    const float* qbase = q + (size_t)b * kMC * kD + (size_t)h * kDH;
    const float* kbase = kk + (kPerB ? (size_t)b * kMC * kD : 0) + (size_t)h * kDH;

    int tid = threadIdx.x;
    int r = tid >> 2, c0 = (tid & 3) * 16;
    {
        const float* qr = qbase + (size_t)(bm + r) * kD + c0;
        #pragma unroll
        for (int u = 0; u < 4; ++u) {
            float4 v = *(const float4*)(qr + u * 4);
            us4v p; p[0] = f2bf(v.x); p[1] = f2bf(v.y); p[2] = f2bf(v.z); p[3] = f2bf(v.w);
            *(us4v*)&As[r][c0 + u * 4] = p;
        }
        int gk = bn + r;
        if (gk < Nk) {
            const float* kr = kbase + (size_t)gk * kD + c0;
            #pragma unroll
            for (int u = 0; u < 4; ++u) {
                float4 v = *(const float4*)(kr + u * 4);
                us4v p; p[0] = f2bf(v.x); p[1] = f2bf(v.y); p[2] = f2bf(v.z); p[3] = f2bf(v.w);
                *(us4v*)&Ks[r][c0 + u * 4] = p;
            }
        } else {
            us4v zz = {};
            #pragma unroll
            for (int u = 0; u < 4; ++u) *(us4v*)&Ks[r][c0 + u * 4] = zz;
        }
    }
    __syncthreads();

    int wid = tid >> 6, lane = tid & 63;
    int wm = (wid >> 1) * 32, wn = (wid & 1) * 32;
    int l15 = lane & 15, lg = lane >> 4;

    f32x4v acc[2][2] = {};
    #pragma unroll
    for (int kc = 0; kc < 2; ++kc) {
        us8v a0 = *(const us8v*)&As[wm + l15][kc * 32 + lg * 8];
        us8v a1 = *(const us8v*)&As[wm + 16 + l15][kc * 32 + lg * 8];
        us8v b0 = *(const us8v*)&Ks[wn + l15][kc * 32 + lg * 8];
        us8v b1 = *(const us8v*)&Ks[wn + 16 + l15][kc * 32 + lg * 8];
        acc[0][0] = mfma_bf16(a0, b0, acc[0][0]);
        acc[0][1] = mfma_bf16(a0, b1, acc[0][1]);
        acc[1][0] = mfma_bf16(a1, b0, acc[1][0]);
        acc[1][1] = mfma_bf16(a1, b1, acc[1][1]);
    }

    #pragma unroll
    for (int fm = 0; fm < 2; ++fm) {
        #pragma unroll
        for (int fn = 0; fn < 2; ++fn) {
            int gj = bn + wn + fn * 16 + l15;
            if (gj >= Nk) continue;
            #pragma unroll
            for (int rr = 0; rr < 4; ++rr) {
                int gi = bm + wm + fm * 16 + lg * 4 + rr;
                float val = acc[fm][fn][rr] * kScale;
                if (cqk && gi < kT)
                    cqk[(((size_t)(b * kH + h)) * kT + gi) * kSA + gj] = val;
                if (selfmask && (gj > gi || gj >= kT)) val = -1e30f;
                sws[((size_t)z * kMC + gi) * sld + gj] = val;
            }
        }
    }
}

// ========================================================================
// Softmax + PV: block handles 4 q-rows of one (b,h). Wave w owns row i0+w:
// phase 1 lane-strided softmax into LDS; phase 2 PV with coalesced V reads.
// ========================================================================
__global__ __launch_bounds__(256)
void k_smpv(const float* __restrict__ sws, const float* __restrict__ vv,
            float* __restrict__ o, int Nk, int sld, int vPerB)
{
    __shared__ float p[4][kSLDc];
    __shared__ float inv[4];
    int z = blockIdx.y, b = z / kH, h = z % kH;
    int i0 = blockIdx.x * 4;
    int t = threadIdx.x, w = t >> 6, ln = t & 63;
    const float* vbase = vv + (vPerB ? (size_t)b * kMC * kD : 0) + (size_t)h * kDH;

    const float* srow = sws + ((size_t)z * kMC + i0 + w) * sld;
    float mx = -3e38f;
    for (int j = ln; j < Nk; j += 64) mx = fmaxf(mx, srow[j]);
    for (int off = 32; off > 0; off >>= 1) mx = fmaxf(mx, __shfl_xor(mx, off));
    float sum = 0.f;
    for (int j = ln; j < Nk; j += 64) {
        float e = expf(srow[j] - mx);
        p[w][j] = e;
        sum += e;
    }
    for (int off = 32; off > 0; off >>= 1) sum += __shfl_xor(sum, off);
    if (ln == 0) inv[w] = 1.f / sum;
    __syncthreads();

    // PV: wave w -> row i0+w, lane -> d
    const float* vb = vbase + ln;
    float a0 = 0.f, a1 = 0.f, a2 = 0.f, a3 = 0.f;
    int j = 0;
    for (; j + 4 <= Nk; j += 4) {
        a0 += p[w][j]     * vb[(size_t)j * kD];
        a1 += p[w][j + 1] * vb[(size_t)(j + 1) * kD];
        a2 += p[w][j + 2] * vb[(size_t)(j + 2) * kD];
        a3 += p[w][j + 3] * vb[(size_t)(j + 3) * kD];
    }
    for (; j < Nk; ++j) a0 += p[w][j] * vb[(size_t)j * kD];
    float acc = (a0 + a1) + (a2 + a3);
    o[(size_t)(b * kMC + i0 + w) * kD + h * kDH + ln] = acc * inv[w];
}

// ========================================================================
extern "C" void kernel_launch(void* const* d_in, const int* in_sizes, int n_in,
                              void* d_out, int out_size, void* d_ws, size_t ws_size,
                              hipStream_t stream)
{
    const int*   x   = (const int*)  d_in[0];
    const float* xa  = (const float*)d_in[1];
    const float* tok = (const float*)d_in[4];
    const float* pos = (const float*)d_in[5];
    const float* attn_ln_g  = (const float*)d_in[6];
    const float* attn_ln_b  = (const float*)d_in[7];
    const float* attn_q_w   = (const float*)d_in[8];
    const float* attn_q_b   = (const float*)d_in[9];
    const float* attn_k_w   = (const float*)d_in[10];
    const float* attn_v_w   = (const float*)d_in[11];
    const float* attn_v_b   = (const float*)d_in[12];
    const float* attn_o_w   = (const float*)d_in[13];
    const float* attn_o_b   = (const float*)d_in[14];
    const float* cross_ln_g = (const float*)d_in[15];
    const float* cross_ln_b = (const float*)d_in[16];
    const float* cross_q_w  = (const float*)d_in[17];
    const float* cross_q_b  = (const float*)d_in[18];
    const float* cross_k_w  = (const float*)d_in[19];
    const float* cross_v_w  = (const float*)d_in[20];
    const float* cross_v_b  = (const float*)d_in[21];
    const float* cross_o_w  = (const float*)d_in[22];
    const float* cross_o_b  = (const float*)d_in[23];
    const float* mlp_ln_g   = (const float*)d_in[24];
    const float* mlp_ln_b   = (const float*)d_in[25];
    const float* mlp_w1     = (const float*)d_in[26];
    const float* mlp_b1     = (const float*)d_in[27];
    const float* mlp_w2     = (const float*)d_in[28];
    const float* mlp_b2     = (const float*)d_in[29];
    const float* ln_g       = (const float*)d_in[30];
    const float* ln_b       = (const float*)d_in[31];

    float* out = (float*)d_out;
    float* h   = (float*)d_ws;
    float* y   = h   + (size_t)kR * kD;
    float* qws = y   + (size_t)kR * kD;
    float* o   = qws + (size_t)kR * kD;
    float* hid = o   + (size_t)kR * kD;
    float* yF  = hid + (size_t)kR * 4 * kD;
    float* sS  = yF  + (size_t)kB * kT * kD;   // scores scratch: 24*256*1504 f32

    auto gemm1 = [&](const float* A, const float* W, const float* bias, const float* res,
                     float* O, int M, int N, int K, int dogelu) {
        GBatch g{};
        g.e[0] = { W, bias, res, O };
        gemm_mfma<<<dim3((M + 63) / 64, (N + 63) / 64, 1), 256, 0, stream>>>(
            A, g, M, N, K, dogelu);
    };

    k_embed<<<kB * kMC * kD / 256, 256, 0, stream>>>(x, tok, pos, h);

    // all cross K/V projections (layer-invariant input xa) in ONE launch
    {
        GBatch gc{};
        for (int l = 0; l < kL; ++l) {
            gc.e[2 * l]     = { cross_k_w + (size_t)l * kD * kD, nullptr, nullptr,
                                out + OFF_CKV + (size_t)(2 * l) * kSA * kD };
            gc.e[2 * l + 1] = { cross_v_w + (size_t)l * kD * kD, cross_v_b + (size_t)l * kD,
                                nullptr,
                                out + OFF_CKV + (size_t)(2 * l + 1) * kSA * kD };
        }
        gemm_mfma<<<dim3((kSA + 63) / 64, kD / 64, 2 * kL), 256, 0, stream>>>(
            xa, gc, kSA, kD, kD, 0);
    }

    for (int l = 0; l < kL; ++l) {
        size_t dd = (size_t)l * kD * kD;
        float* kbuf  = out + OFF_MKV + (size_t)(2 * l)     * kB * kMC * kD;
        float* vbuf  = out + OFF_MKV + (size_t)(2 * l + 1) * kB * kMC * kD;
        float* ckbuf = out + OFF_CKV + (size_t)(2 * l)     * kSA * kD;
        float* cvbuf = out + OFF_CKV + (size_t)(2 * l + 1) * kSA * kD;
        float* cqk   = out + OFF_CQK + (size_t)l * kB * kH * kT * kSA;

        // --- self attention ---
        k_ln<<<kR, 256, 0, stream>>>(h, attn_ln_g + l * kD, attn_ln_b + l * kD, y);
        {
            GBatch g3{};
            g3.e[0] = { attn_q_w + dd, attn_q_b + (size_t)l * kD, nullptr, qws };
            g3.e[1] = { attn_k_w + dd, nullptr,                   nullptr, kbuf };
            g3.e[2] = { attn_v_w + dd, attn_v_b + (size_t)l * kD, nullptr, vbuf };
            gemm_mfma<<<dim3(kR / 64, kD / 64, 3), 256, 0, stream>>>(y, g3, kR, kD, kD, 0);
        }
        k_scores<<<dim3(kMC / 64, kMC / 64, kB * kH), 256, 0, stream>>>(
            qws, kbuf, sS, nullptr, kMC, kMC, 1, 1);
        k_smpv<<<dim3(kMC / 4, kB * kH), 256, 0, stream>>>(sS, vbuf, o, kMC, kMC, 1);
        gemm1(o, attn_o_w + dd, attn_o_b + l * kD, h, h, kR, kD, kD, 0);

        // --- cross attention ---
        k_ln<<<kR, 256, 0, stream>>>(h, cross_ln_g + l * kD, cross_ln_b + l * kD, y);
        gemm1(y, cross_q_w + dd, cross_q_b + l * kD, nullptr, qws, kR, kD, kD, 0);
        k_scores<<<dim3(kMC / 64, (kSA + 63) / 64, kB * kH), 256, 0, stream>>>(
            qws, ckbuf, sS, cqk, kSA, kSLDc, 0, 0);
        k_smpv<<<dim3(kMC / 4, kB * kH), 256, 0, stream>>>(sS, cvbuf, o, kSA, kSLDc, 0);
        gemm1(o, cross_o_w + dd, cross_o_b + l * kD, h, h, kR, kD, kD, 0);

        // --- MLP ---
        k_ln<<<kR, 256, 0, stream>>>(h, mlp_ln_g + l * kD, mlp_ln_b + l * kD, y);
        gemm1(y,   mlp_w1 + (size_t)l * 4 * kD * kD, mlp_b1 + (size_t)l * 4 * kD,
              nullptr, hid, kR, 4 * kD, kD, 1);
        gemm1(hid, mlp_w2 + (size_t)l * 4 * kD * kD, mlp_b2 + l * kD,
              h, h, kR, kD, 4 * kD, 0);
    }

    k_finalln<<<kB * kT, 256, 0, stream>>>(h, ln_g, ln_b, yF);
    gemm1(yF, tok, nullptr, nullptr, out, kB * kT, kV, kD, 0);
}

// Round 4
// 4428.225 us; speedup vs baseline: 5.2654x; 1.6665x over previous
//
#include <hip/hip_runtime.h>
#include <math.h>

// ---- problem constants --------------------------------------------------
constexpr int kL = 12, kD = 768, kH = 12, kV = 51865, kSA = 1500;
constexpr int kB = 2, kT = 192, kMC = 256, kDH = 64;
constexpr float kScale = 0.125f;      // DH^-0.5
constexpr float kEps = 1e-5f;
constexpr int kR = kB * kMC;          // 512 rows through the layer stack
constexpr int kSLDc = 1504;           // cross score row stride (pad)

// ---- d_out layout (flat float32, reference return order) ---------------
constexpr size_t SZ_LOGITS = (size_t)kB * kT * kV;
constexpr size_t SZ_CQK    = (size_t)kL * kB * kH * kT * kSA;
constexpr size_t SZ_MKV    = (size_t)2 * kL * kB * kMC * kD;
constexpr size_t OFF_CQK = SZ_LOGITS;
constexpr size_t OFF_MKV = OFF_CQK + SZ_CQK;
constexpr size_t OFF_CKV = OFF_MKV + SZ_MKV;

typedef float f32x4v __attribute__((ext_vector_type(4)));
typedef unsigned short us8v __attribute__((ext_vector_type(8)));
typedef unsigned short us4v __attribute__((ext_vector_type(4)));

static __device__ __forceinline__ unsigned short f2bf(float f) {
    unsigned int u = __float_as_uint(f);
    u += 0x7fffu + ((u >> 16) & 1u);          // round-to-nearest-even
    return (unsigned short)(u >> 16);
}

static __device__ __forceinline__ f32x4v mfma_bf16(us8v a, us8v b, f32x4v c) {
    asm("v_mfma_f32_16x16x32_bf16 %0, %1, %2, %0" : "+v"(c) : "v"(a), "v"(b));
    return c;
}

// ========================================================================
// embedding
// ========================================================================
__global__ void k_embed(const int* __restrict__ x, const float* __restrict__ tok,
                        const float* __restrict__ pos, float* __restrict__ h)
{
    int idx = blockIdx.x * 256 + threadIdx.x;
    int d = idx % kD;
    int t = (idx / kD) % kMC;
    int b = idx / (kD * kMC);
    float v = 0.f;
    if (t < kT) {
        int tokid = x[b * kT + t];
        v = tok[(size_t)tokid * kD + d] + pos[(size_t)t * kD + d];
    }
    h[idx] = v;
}

// ========================================================================
// LayerNorm (256 thr per row of 768) -> bf16 output
// ========================================================================
__global__ void k_ln(const float* __restrict__ in, const float* __restrict__ g,
                     const float* __restrict__ bb, unsigned short* __restrict__ out)
{
    int r = blockIdx.x;
    const float* xr = in + (size_t)r * kD;
    int t = threadIdx.x;
    float x0 = xr[t], x1 = xr[t + 256], x2 = xr[t + 512];
    float s  = x0 + x1 + x2;
    float sq = x0 * x0 + x1 * x1 + x2 * x2;
    __shared__ float red[8];
    for (int o = 32; o > 0; o >>= 1) { s += __shfl_down(s, o); sq += __shfl_down(sq, o); }
    int w = t >> 6;
    if ((t & 63) == 0) { red[w] = s; red[4 + w] = sq; }
    __syncthreads();
    s  = red[0] + red[1] + red[2] + red[3];
    sq = red[4] + red[5] + red[6] + red[7];
    float m   = s * (1.f / kD);
    float var = sq * (1.f / kD) - m * m;
    float rs  = rsqrtf(var + kEps);
    unsigned short* orow = out + (size_t)r * kD;
    orow[t]       = f2bf((x0 - m) * rs * g[t]       + bb[t]);
    orow[t + 256] = f2bf((x1 - m) * rs * g[t + 256] + bb[t + 256]);
    orow[t + 512] = f2bf((x2 - m) * rs * g[t + 512] + bb[t + 512]);
}

__global__ void k_finalln(const float* __restrict__ h, const float* __restrict__ g,
                          const float* __restrict__ bb, unsigned short* __restrict__ out)
{
    int r = blockIdx.x;                 // 0..kB*kT
    int b = r / kT, tt = r % kT;
    const float* xr = h + (size_t)(b * kMC + tt) * kD;
    int t = threadIdx.x;
    float x0 = xr[t], x1 = xr[t + 256], x2 = xr[t + 512];
    float s  = x0 + x1 + x2;
    float sq = x0 * x0 + x1 * x1 + x2 * x2;
    __shared__ float red[8];
    for (int o = 32; o > 0; o >>= 1) { s += __shfl_down(s, o); sq += __shfl_down(sq, o); }
    int w = t >> 6;
    if ((t & 63) == 0) { red[w] = s; red[4 + w] = sq; }
    __syncthreads();
    s  = red[0] + red[1] + red[2] + red[3];
    sq = red[4] + red[5] + red[6] + red[7];
    float m   = s * (1.f / kD);
    float var = sq * (1.f / kD) - m * m;
    float rs  = rsqrtf(var + kEps);
    unsigned short* orow = out + (size_t)r * kD;
    orow[t]       = f2bf((x0 - m) * rs * g[t]       + bb[t]);
    orow[t + 256] = f2bf((x1 - m) * rs * g[t + 256] + bb[t + 256]);
    orow[t + 512] = f2bf((x2 - m) * rs * g[t + 512] + bb[t + 512]);
}

// ========================================================================
// bf16-MFMA GEMM, z-batched via pointer table. BK=64, BM=BN=64.
// ABF: A is bf16 (else fp32, converted in staging). W always fp32.
// OBF: output bf16 (no residual) else fp32 (+optional residual).
// mtiles: M-tiles processed inside the block (W stays cache-hot).
// ========================================================================
struct GEntry { const float* W; const float* bias; const float* res; void* out; };
struct GBatch { GEntry e[24]; };

template <int ABF, int OBF>
__global__ __launch_bounds__(256)
void gemm_t(const void* __restrict__ Av, GBatch gb, int M, int N, int K,
            int dogelu, int mtiles)
{
    constexpr int LD = 72;                        // bf16 row stride (pad 8); 144B = 9*16B
    __shared__ unsigned short As[64][LD];
    __shared__ unsigned short Ws[64][LD];
    const GEntry ge = gb.e[blockIdx.z];
    const float* __restrict__ W = ge.W;
    int bn = blockIdx.y * 64;
    int tid = threadIdx.x;
    int wid = tid >> 6, lane = tid & 63;
    int wm = (wid >> 1) * 32, wn = (wid & 1) * 32;
    int l15 = lane & 15, lg = lane >> 4;
    int r = tid >> 2, cq = (tid & 3) * 16;        // staging: 64 rows x 64 k

    for (int mt = 0; mt < mtiles; ++mt) {
        int bm = (blockIdx.x * mtiles + mt) * 64;
        f32x4v acc00 = {}, acc01 = {}, acc10 = {}, acc11 = {};
        for (int k0 = 0; k0 < K; k0 += 64) {
            int gr = bm + r;
            if (ABF) {
                const unsigned short* A = (const unsigned short*)Av;
                us8v v0 = {}, v1 = {};
                if (gr < M) {
                    const unsigned short* ar = A + (size_t)gr * K + k0 + cq;
                    v0 = *(const us8v*)ar;
                    v1 = *(const us8v*)(ar + 8);
                }
                *(us8v*)&As[r][cq]     = v0;
                *(us8v*)&As[r][cq + 8] = v1;
            } else {
                const float* A = (const float*)Av;
                us4v p0 = {}, p1 = {}, p2 = {}, p3 = {};
                if (gr < M) {
                    const float* ar = A + (size_t)gr * K + k0 + cq;
                    float4 v0 = *(const float4*)(ar);
                    float4 v1 = *(const float4*)(ar + 4);
                    float4 v2 = *(const float4*)(ar + 8);
                    float4 v3 = *(const float4*)(ar + 12);
                    p0[0]=f2bf(v0.x); p0[1]=f2bf(v0.y); p0[2]=f2bf(v0.z); p0[3]=f2bf(v0.w);
                    p1[0]=f2bf(v1.x); p1[1]=f2bf(v1.y); p1[2]=f2bf(v1.z); p1[3]=f2bf(v1.w);
                    p2[0]=f2bf(v2.x); p2[1]=f2bf(v2.y); p2[2]=f2bf(v2.z); p2[3]=f2bf(v2.w);
                    p3[0]=f2bf(v3.x); p3[1]=f2bf(v3.y); p3[2]=f2bf(v3.z); p3[3]=f2bf(v3.w);
                }
                *(us4v*)&As[r][cq]      = p0;
                *(us4v*)&As[r][cq + 4]  = p1;
                *(us4v*)&As[r][cq + 8]  = p2;
                *(us4v*)&As[r][cq + 12] = p3;
            }
            {
                int gc = bn + r;
                us4v p0 = {}, p1 = {}, p2 = {}, p3 = {};
                if (gc < N) {
                    const float* wr = W + (size_t)gc * K + k0 + cq;
                    float4 v0 = *(const float4*)(wr);
                    float4 v1 = *(const float4*)(wr + 4);
                    float4 v2 = *(const float4*)(wr + 8);
                    float4 v3 = *(const float4*)(wr + 12);
                    p0[0]=f2bf(v0.x); p0[1]=f2bf(v0.y); p0[2]=f2bf(v0.z); p0[3]=f2bf(v0.w);
                    p1[0]=f2bf(v1.x); p1[1]=f2bf(v1.y); p1[2]=f2bf(v1.z); p1[3]=f2bf(v1.w);
                    p2[0]=f2bf(v2.x); p2[1]=f2bf(v2.y); p2[2]=f2bf(v2.z); p2[3]=f2bf(v2.w);
                    p3[0]=f2bf(v3.x); p3[1]=f2bf(v3.y); p3[2]=f2bf(v3.z); p3[3]=f2bf(v3.w);
                }
                *(us4v*)&Ws[r][cq]      = p0;
                *(us4v*)&Ws[r][cq + 4]  = p1;
                *(us4v*)&Ws[r][cq + 8]  = p2;
                *(us4v*)&Ws[r][cq + 12] = p3;
            }
            __syncthreads();
            #pragma unroll
            for (int kc = 0; kc < 2; ++kc) {
                us8v af0 = *(const us8v*)&As[wm + l15][kc * 32 + lg * 8];
                us8v af1 = *(const us8v*)&As[wm + 16 + l15][kc * 32 + lg * 8];
                us8v wf0 = *(const us8v*)&Ws[wn + l15][kc * 32 + lg * 8];
                us8v wf1 = *(const us8v*)&Ws[wn + 16 + l15][kc * 32 + lg * 8];
                acc00 = mfma_bf16(af0, wf0, acc00);
                acc01 = mfma_bf16(af0, wf1, acc01);
                acc10 = mfma_bf16(af1, wf0, acc10);
                acc11 = mfma_bf16(af1, wf1, acc11);
            }
            __syncthreads();
        }
        const float* bias = ge.bias;
        const float* res  = ge.res;
        f32x4v accs[2][2] = { { acc00, acc01 }, { acc10, acc11 } };
        #pragma unroll
        for (int fi = 0; fi < 2; ++fi) {
            #pragma unroll
            for (int fj = 0; fj < 2; ++fj) {
                int col = bn + wn + fj * 16 + l15;
                if (col >= N) continue;
                float bv = bias ? bias[col] : 0.f;
                #pragma unroll
                for (int rr = 0; rr < 4; ++rr) {
                    int row = bm + wm + fi * 16 + lg * 4 + rr;
                    if (row >= M) continue;
                    float v = accs[fi][fj][rr] + bv;
                    if (dogelu) v = 0.5f * v * (1.f + erff(v * 0.70710678118654752f));
                    if (OBF) {
                        ((unsigned short*)ge.out)[(size_t)row * N + col] = f2bf(v);
                    } else {
                        if (res) v += res[(size_t)row * N + col];
                        ((float*)ge.out)[(size_t)row * N + col] = v;
                    }
                }
            }
        }
        if (mt + 1 < mtiles) __syncthreads();
    }
}

// ========================================================================
// Attention scores via MFMA: S[z][i][j] = scale * Q[i,:]·K[j,:]  (z = b*12+h)
// QBF: q is bf16. K always fp32 (it lives in the output buffer).
// ========================================================================
template <int QBF>
__global__ __launch_bounds__(256)
void k_scores(const void* __restrict__ qv, const float* __restrict__ kk,
              float* __restrict__ sws, float* __restrict__ cqk,
              int Nk, int sld, int selfmask, int kPerB)
{
    constexpr int LD = 72;
    __shared__ unsigned short As[64][LD];
    __shared__ unsigned short Ks[64][LD];
    int z = blockIdx.z, b = z / kH, h = z % kH;
    int bm = blockIdx.x * 64, bn = blockIdx.y * 64;
    const float* kbase = kk + (kPerB ? (size_t)b * kMC * kD : 0) + (size_t)h * kDH;

    int tid = threadIdx.x;
    int r = tid >> 2, c0 = (tid & 3) * 16;
    {
        if (QBF) {
            const unsigned short* q = (const unsigned short*)qv;
            const unsigned short* qr =
                q + (size_t)(b * kMC + bm + r) * kD + h * kDH + c0;
            *(us8v*)&As[r][c0]     = *(const us8v*)qr;
            *(us8v*)&As[r][c0 + 8] = *(const us8v*)(qr + 8);
        } else {
            const float* q = (const float*)qv;
            const float* qr = q + (size_t)(b * kMC + bm + r) * kD + h * kDH + c0;
            #pragma unroll
            for (int u = 0; u < 4; ++u) {
                float4 v = *(const float4*)(qr + u * 4);
                us4v p; p[0]=f2bf(v.x); p[1]=f2bf(v.y); p[2]=f2bf(v.z); p[3]=f2bf(v.w);
                *(us4v*)&As[r][c0 + u * 4] = p;
            }
        }
        int gk = bn + r;
        if (gk < Nk) {
            const float* kr = kbase + (size_t)gk * kD + c0;
            #pragma unroll
            for (int u = 0; u < 4; ++u) {
                float4 v = *(const float4*)(kr + u * 4);
                us4v p; p[0]=f2bf(v.x); p[1]=f2bf(v.y); p[2]=f2bf(v.z); p[3]=f2bf(v.w);
                *(us4v*)&Ks[r][c0 + u * 4] = p;
            }
        } else {
            us4v zz = {};
            #pragma unroll
            for (int u = 0; u < 4; ++u) *(us4v*)&Ks[r][c0 + u * 4] = zz;
        }
    }
    __syncthreads();

    int wid = tid >> 6, lane = tid & 63;
    int wm = (wid >> 1) * 32, wn = (wid & 1) * 32;
    int l15 = lane & 15, lg = lane >> 4;

    f32x4v acc[2][2] = {};
    #pragma unroll
    for (int kc = 0; kc < 2; ++kc) {
        us8v a0 = *(const us8v*)&As[wm + l15][kc * 32 + lg * 8];
        us8v a1 = *(const us8v*)&As[wm + 16 + l15][kc * 32 + lg * 8];
        us8v b0 = *(const us8v*)&Ks[wn + l15][kc * 32 + lg * 8];
        us8v b1 = *(const us8v*)&Ks[wn + 16 + l15][kc * 32 + lg * 8];
        acc[0][0] = mfma_bf16(a0, b0, acc[0][0]);
        acc[0][1] = mfma_bf16(a0, b1, acc[0][1]);
        acc[1][0] = mfma_bf16(a1, b0, acc[1][0]);
        acc[1][1] = mfma_bf16(a1, b1, acc[1][1]);
    }

    #pragma unroll
    for (int fm = 0; fm < 2; ++fm) {
        #pragma unroll
        for (int fn = 0; fn < 2; ++fn) {
            int gj = bn + wn + fn * 16 + l15;
            if (gj >= Nk) continue;
            #pragma unroll
            for (int rr = 0; rr < 4; ++rr) {
                int gi = bm + wm + fm * 16 + lg * 4 + rr;
                float val = acc[fm][fn][rr] * kScale;
                if (cqk && gi < kT)
                    cqk[(((size_t)(b * kH + h)) * kT + gi) * kSA + gj] = val;
                if (selfmask && (gj > gi || gj >= kT)) val = -1e30f;
                sws[((size_t)z * kMC + gi) * sld + gj] = val;
            }
        }
    }
}

// ========================================================================
// Softmax + PV: block = 4 q-rows of one (b,h); wave w owns row i0+w.
// Phase 1: lane-strided softmax into LDS. Phase 2: float4 PV, lane=(jj,d4),
// 4 keys in flight per wave, shuffle-reduce over jj. bf16 output.
// ========================================================================
__global__ __launch_bounds__(256)
void k_smpv(const float* __restrict__ sws, const float* __restrict__ vv,
            unsigned short* __restrict__ o, int Nk, int sld, int vPerB)
{
    __shared__ float p[4][kSLDc];
    __shared__ float inv[4];
    int z = blockIdx.y, b = z / kH, h = z % kH;
    int i0 = blockIdx.x * 4;
    int t = threadIdx.x, w = t >> 6, ln = t & 63;

    const float* srow = sws + ((size_t)z * kMC + i0 + w) * sld;
    float mx = -3e38f;
    for (int j = ln; j < Nk; j += 64) mx = fmaxf(mx, srow[j]);
    for (int off = 32; off > 0; off >>= 1) mx = fmaxf(mx, __shfl_xor(mx, off));
    float sum = 0.f;
    for (int j = ln; j < Nk; j += 64) {
        float e = expf(srow[j] - mx);
        p[w][j] = e;
        sum += e;
    }
    for (int off = 32; off > 0; off >>= 1) sum += __shfl_xor(sum, off);
    if (ln == 0) inv[w] = 1.f / sum;
    __syncthreads();

    int jj = ln >> 4, d4 = ln & 15;
    const float* vbase = vv + (vPerB ? (size_t)b * kMC * kD : 0)
                            + (size_t)h * kDH + d4 * 4;
    float ax = 0.f, ay = 0.f, az = 0.f, aw = 0.f;
    for (int j = 0; j < Nk; j += 4) {
        float pv = p[w][j + jj];
        float4 v = *(const float4*)(vbase + (size_t)(j + jj) * kD);
        ax += pv * v.x; ay += pv * v.y; az += pv * v.z; aw += pv * v.w;
    }
    #pragma unroll
    for (int off = 16; off <= 32; off <<= 1) {
        ax += __shfl_xor(ax, off);
        ay += __shfl_xor(ay, off);
        az += __shfl_xor(az, off);
        aw += __shfl_xor(aw, off);
    }
    if (jj == 0) {
        float iv = inv[w];
        us4v pk;
        pk[0] = f2bf(ax * iv); pk[1] = f2bf(ay * iv);
        pk[2] = f2bf(az * iv); pk[3] = f2bf(aw * iv);
        *(us4v*)&o[(size_t)(b * kMC + i0 + w) * kD + h * kDH + d4 * 4] = pk;
    }
}

// ========================================================================
extern "C" void kernel_launch(void* const* d_in, const int* in_sizes, int n_in,
                              void* d_out, int out_size, void* d_ws, size_t ws_size,
                              hipStream_t stream)
{
    const int*   x   = (const int*)  d_in[0];
    const float* xa  = (const float*)d_in[1];
    const float* tok = (const float*)d_in[4];
    const float* pos = (const float*)d_in[5];
    const float* attn_ln_g  = (const float*)d_in[6];
    const float* attn_ln_b  = (const float*)d_in[7];
    const float* attn_q_w   = (const float*)d_in[8];
    const float* attn_q_b   = (const float*)d_in[9];
    const float* attn_k_w   = (const float*)d_in[10];
    const float* attn_v_w   = (const float*)d_in[11];
    const float* attn_v_b   = (const float*)d_in[12];
    const float* attn_o_w   = (const float*)d_in[13];
    const float* attn_o_b   = (const float*)d_in[14];
    const float* cross_ln_g = (const float*)d_in[15];
    const float* cross_ln_b = (const float*)d_in[16];
    const float* cross_q_w  = (const float*)d_in[17];
    const float* cross_q_b  = (const float*)d_in[18];
    const float* cross_k_w  = (const float*)d_in[19];
    const float* cross_v_w  = (const float*)d_in[20];
    const float* cross_v_b  = (const float*)d_in[21];
    const float* cross_o_w  = (const float*)d_in[22];
    const float* cross_o_b  = (const float*)d_in[23];
    const float* mlp_ln_g   = (const float*)d_in[24];
    const float* mlp_ln_b   = (const float*)d_in[25];
    const float* mlp_w1     = (const float*)d_in[26];
    const float* mlp_b1     = (const float*)d_in[27];
    const float* mlp_w2     = (const float*)d_in[28];
    const float* mlp_b2     = (const float*)d_in[29];
    const float* ln_g       = (const float*)d_in[30];
    const float* ln_b       = (const float*)d_in[31];

    float* out = (float*)d_out;
    // fp32 scratch first (alignment), then bf16 scratch
    float* h    = (float*)d_ws;                          // 512*768 f32
    float* qws  = h   + (size_t)kR * kD;                 // 512*768 f32 (self q)
    float* sS   = qws + (size_t)kR * kD;                 // 24*256*1504 f32
    unsigned short* y16   = (unsigned short*)(sS + (size_t)kB * kH * kMC * kSLDc);
    unsigned short* qb16  = y16  + (size_t)kR * kD;      // cross q bf16
    unsigned short* o16   = qb16 + (size_t)kR * kD;      // attn out bf16
    unsigned short* hid16 = o16  + (size_t)kR * kD;      // MLP hidden bf16
    unsigned short* yF16  = hid16 + (size_t)kR * 4 * kD; // final LN bf16

    k_embed<<<kB * kMC * kD / 256, 256, 0, stream>>>(x, tok, pos, h);

    // all cross K/V projections (layer-invariant input xa) in ONE launch
    {
        GBatch gc{};
        for (int l = 0; l < kL; ++l) {
            gc.e[2 * l]     = { cross_k_w + (size_t)l * kD * kD, nullptr, nullptr,
                                out + OFF_CKV + (size_t)(2 * l) * kSA * kD };
            gc.e[2 * l + 1] = { cross_v_w + (size_t)l * kD * kD, cross_v_b + (size_t)l * kD,
                                nullptr,
                                out + OFF_CKV + (size_t)(2 * l + 1) * kSA * kD };
        }
        gemm_t<0, 0><<<dim3((kSA + 63) / 64, kD / 64, 2 * kL), 256, 0, stream>>>(
            xa, gc, kSA, kD, kD, 0, 1);
    }

    for (int l = 0; l < kL; ++l) {
        size_t dd = (size_t)l * kD * kD;
        float* kbuf  = out + OFF_MKV + (size_t)(2 * l)     * kB * kMC * kD;
        float* vbuf  = out + OFF_MKV + (size_t)(2 * l + 1) * kB * kMC * kD;
        float* ckbuf = out + OFF_CKV + (size_t)(2 * l)     * kSA * kD;
        float* cvbuf = out + OFF_CKV + (size_t)(2 * l + 1) * kSA * kD;
        float* cqk   = out + OFF_CQK + (size_t)l * kB * kH * kT * kSA;

        // --- self attention ---
        k_ln<<<kR, 256, 0, stream>>>(h, attn_ln_g + l * kD, attn_ln_b + l * kD, y16);
        {
            GBatch g3{};
            g3.e[0] = { attn_q_w + dd, attn_q_b + (size_t)l * kD, nullptr, qws };
            g3.e[1] = { attn_k_w + dd, nullptr,                   nullptr, kbuf };
            g3.e[2] = { attn_v_w + dd, attn_v_b + (size_t)l * kD, nullptr, vbuf };
            gemm_t<1, 0><<<dim3(kR / 64, kD / 64, 3), 256, 0, stream>>>(
                y16, g3, kR, kD, kD, 0, 1);
        }
        k_scores<0><<<dim3(kMC / 64, kMC / 64, kB * kH), 256, 0, stream>>>(
            qws, kbuf, sS, nullptr, kMC, kMC, 1, 1);
        k_smpv<<<dim3(kMC / 4, kB * kH), 256, 0, stream>>>(sS, vbuf, o16, kMC, kMC, 1);
        {
            GBatch g1{};
            g1.e[0] = { attn_o_w + dd, attn_o_b + (size_t)l * kD, h, h };
            gemm_t<1, 0><<<dim3(kR / 64, kD / 64, 1), 256, 0, stream>>>(
                o16, g1, kR, kD, kD, 0, 1);
        }

        // --- cross attention ---
        k_ln<<<kR, 256, 0, stream>>>(h, cross_ln_g + l * kD, cross_ln_b + l * kD, y16);
        {
            GBatch g1{};
            g1.e[0] = { cross_q_w + dd, cross_q_b + (size_t)l * kD, nullptr, qb16 };
            gemm_t<1, 1><<<dim3(kR / 64, kD / 64, 1), 256, 0, stream>>>(
                y16, g1, kR, kD, kD, 0, 1);
        }
        k_scores<1><<<dim3(kMC / 64, (kSA + 63) / 64, kB * kH), 256, 0, stream>>>(
            qb16, ckbuf, sS, cqk, kSA, kSLDc, 0, 0);
        k_smpv<<<dim3(kMC / 4, kB * kH), 256, 0, stream>>>(sS, cvbuf, o16, kSA, kSLDc, 0);
        {
            GBatch g1{};
            g1.e[0] = { cross_o_w + dd, cross_o_b + (size_t)l * kD, h, h };
            gemm_t<1, 0><<<dim3(kR / 64, kD / 64, 1), 256, 0, stream>>>(
                o16, g1, kR, kD, kD, 0, 1);
        }

        // --- MLP ---
        k_ln<<<kR, 256, 0, stream>>>(h, mlp_ln_g + l * kD, mlp_ln_b + l * kD, y16);
        {
            GBatch g1{};
            g1.e[0] = { mlp_w1 + (size_t)l * 4 * kD * kD, mlp_b1 + (size_t)l * 4 * kD,
                        nullptr, hid16 };
            gemm_t<1, 1><<<dim3(kR / 64, 4 * kD / 64, 1), 256, 0, stream>>>(
                y16, g1, kR, 4 * kD, kD, 1, 1);
        }
        {
            GBatch g1{};
            g1.e[0] = { mlp_w2 + (size_t)l * 4 * kD * kD, mlp_b2 + (size_t)l * kD, h, h };
            gemm_t<1, 0><<<dim3(kR / 64, kD / 64, 1), 256, 0, stream>>>(
                hid16, g1, kR, kD, 4 * kD, 0, 1);
        }
    }

    k_finalln<<<kB * kT, 256, 0, stream>>>(h, ln_g, ln_b, yF16);
    {
        // logits: M=384 processed as 6 in-block M-tiles so each block streams
        // the tok_emb panel once (it is the HBM-dominant read of the model).
        GBatch g1{};
        g1.e[0] = { tok, nullptr, nullptr, out };
        gemm_t<1, 0><<<dim3(1, (kV + 63) / 64, 1), 256, 0, stream>>>(
            yF16, g1, kB * kT, kV, kD, 0, 6);
    }
}

// Round 7
// 4348.364 us; speedup vs baseline: 5.3621x; 1.0184x over previous
//
#include <hip/hip_runtime.h>
#include <math.h>

// ---- problem constants --------------------------------------------------
constexpr int kL = 12, kD = 768, kH = 12, kV = 51865, kSA = 1500;
constexpr int kB = 2, kT = 192, kMC = 256, kDH = 64;
constexpr float kScale = 0.125f;      // DH^-0.5
constexpr float kEps = 1e-5f;
constexpr int kR = kB * kMC;          // 512 rows through the layer stack
constexpr int kSLDc = 1504;           // cross score row stride (pad)

// ---- d_out layout (flat float32, reference return order) ---------------
constexpr size_t SZ_LOGITS = (size_t)kB * kT * kV;
constexpr size_t SZ_CQK    = (size_t)kL * kB * kH * kT * kSA;
constexpr size_t SZ_MKV    = (size_t)2 * kL * kB * kMC * kD;
constexpr size_t OFF_CQK = SZ_LOGITS;
constexpr size_t OFF_MKV = OFF_CQK + SZ_CQK;
constexpr size_t OFF_CKV = OFF_MKV + SZ_MKV;

typedef float f32x4v __attribute__((ext_vector_type(4)));
typedef unsigned short us8v __attribute__((ext_vector_type(8)));
typedef unsigned short us4v __attribute__((ext_vector_type(4)));
typedef unsigned int   u32x2 __attribute__((ext_vector_type(2)));
typedef unsigned int   u32x4 __attribute__((ext_vector_type(4)));

static __device__ __forceinline__ unsigned short f2bf(float f) {
    unsigned int u = __float_as_uint(f);
    u += 0x7fffu + ((u >> 16) & 1u);          // round-to-nearest-even
    return (unsigned short)(u >> 16);
}

// packed f32x2 -> bf16x2 (RNE), low half from `lo` (guide T12 recipe)
static __device__ __forceinline__ unsigned int f2bf2(float lo, float hi) {
    unsigned int r;
    asm("v_cvt_pk_bf16_f32 %0, %1, %2" : "=v"(r) : "v"(lo), "v"(hi));
    return r;
}

static __device__ __forceinline__ f32x4v mfma_bf16(us8v a, us8v b, f32x4v c) {
    asm("v_mfma_f32_16x16x32_bf16 %0, %1, %2, %0" : "+v"(c) : "v"(a), "v"(b));
    return c;
}

// ========================================================================
// embedding
// ========================================================================
__global__ void k_embed(const int* __restrict__ x, const float* __restrict__ tok,
                        const float* __restrict__ pos, float* __restrict__ h)
{
    int idx = blockIdx.x * 256 + threadIdx.x;
    int d = idx % kD;
    int t = (idx / kD) % kMC;
    int b = idx / (kD * kMC);
    float v = 0.f;
    if (t < kT) {
        int tokid = x[b * kT + t];
        v = tok[(size_t)tokid * kD + d] + pos[(size_t)t * kD + d];
    }
    h[idx] = v;
}

// ========================================================================
// LayerNorm (256 thr per row of 768) -> bf16 output
// ========================================================================
__global__ void k_ln(const float* __restrict__ in, const float* __restrict__ g,
                     const float* __restrict__ bb, unsigned short* __restrict__ out)
{
    int r = blockIdx.x;
    const float* xr = in + (size_t)r * kD;
    int t = threadIdx.x;
    float x0 = xr[t], x1 = xr[t + 256], x2 = xr[t + 512];
    float s  = x0 + x1 + x2;
    float sq = x0 * x0 + x1 * x1 + x2 * x2;
    __shared__ float red[8];
    for (int o = 32; o > 0; o >>= 1) { s += __shfl_down(s, o); sq += __shfl_down(sq, o); }
    int w = t >> 6;
    if ((t & 63) == 0) { red[w] = s; red[4 + w] = sq; }
    __syncthreads();
    s  = red[0] + red[1] + red[2] + red[3];
    sq = red[4] + red[5] + red[6] + red[7];
    float m   = s * (1.f / kD);
    float var = sq * (1.f / kD) - m * m;
    float rs  = rsqrtf(var + kEps);
    unsigned short* orow = out + (size_t)r * kD;
    orow[t]       = f2bf((x0 - m) * rs * g[t]       + bb[t]);
    orow[t + 256] = f2bf((x1 - m) * rs * g[t + 256] + bb[t + 256]);
    orow[t + 512] = f2bf((x2 - m) * rs * g[t + 512] + bb[t + 512]);
}

__global__ void k_finalln(const float* __restrict__ h, const float* __restrict__ g,
                          const float* __restrict__ bb, unsigned short* __restrict__ out)
{
    int r = blockIdx.x;                 // 0..kB*kT
    int b = r / kT, tt = r % kT;
    const float* xr = h + (size_t)(b * kMC + tt) * kD;
    int t = threadIdx.x;
    float x0 = xr[t], x1 = xr[t + 256], x2 = xr[t + 512];
    float s  = x0 + x1 + x2;
    float sq = x0 * x0 + x1 * x1 + x2 * x2;
    __shared__ float red[8];
    for (int o = 32; o > 0; o >>= 1) { s += __shfl_down(s, o); sq += __shfl_down(sq, o); }
    int w = t >> 6;
    if ((t & 63) == 0) { red[w] = s; red[4 + w] = sq; }
    __syncthreads();
    s  = red[0] + red[1] + red[2] + red[3];
    sq = red[4] + red[5] + red[6] + red[7];
    float m   = s * (1.f / kD);
    float var = sq * (1.f / kD) - m * m;
    float rs  = rsqrtf(var + kEps);
    unsigned short* orow = out + (size_t)r * kD;
    orow[t]       = f2bf((x0 - m) * rs * g[t]       + bb[t]);
    orow[t + 256] = f2bf((x1 - m) * rs * g[t + 256] + bb[t + 256]);
    orow[t + 512] = f2bf((x2 - m) * rs * g[t + 512] + bb[t + 512]);
}

// ========================================================================
// bf16-MFMA GEMM, z-batched via pointer table. BK=64, BM=BN=64.
// Staging conversions use v_cvt_pk_bf16_f32 (same RNE as f2bf).
// ========================================================================
struct GEntry { const float* W; const float* bias; const float* res; void* out; };
struct GBatch { GEntry e[24]; };

template <int ABF, int OBF>
__global__ __launch_bounds__(256)
void gemm_t(const void* __restrict__ Av, GBatch gb, int M, int N, int K,
            int dogelu, int mtiles)
{
    constexpr int LD = 72;
    __shared__ unsigned short As[64][LD];
    __shared__ unsigned short Ws[64][LD];
    const GEntry ge = gb.e[blockIdx.z];
    const float* __restrict__ W = ge.W;
    int bn = blockIdx.y * 64;
    int tid = threadIdx.x;
    int wid = tid >> 6, lane = tid & 63;
    int wm = (wid >> 1) * 32, wn = (wid & 1) * 32;
    int l15 = lane & 15, lg = lane >> 4;
    int r = tid >> 2, cq = (tid & 3) * 16;

    for (int mt = 0; mt < mtiles; ++mt) {
        int bm = (blockIdx.x * mtiles + mt) * 64;
        f32x4v acc00 = {}, acc01 = {}, acc10 = {}, acc11 = {};
        for (int k0 = 0; k0 < K; k0 += 64) {
            int gr = bm + r;
            if (ABF) {
                const unsigned short* A = (const unsigned short*)Av;
                us8v v0 = {}, v1 = {};
                if (gr < M) {
                    const unsigned short* ar = A + (size_t)gr * K + k0 + cq;
                    v0 = *(const us8v*)ar;
                    v1 = *(const us8v*)(ar + 8);
                }
                *(us8v*)&As[r][cq]     = v0;
                *(us8v*)&As[r][cq + 8] = v1;
            } else {
                const float* A = (const float*)Av;
                u32x4 pa0 = {}, pa1 = {};
                if (gr < M) {
                    const float* ar = A + (size_t)gr * K + k0 + cq;
                    float4 v0 = *(const float4*)(ar);
                    float4 v1 = *(const float4*)(ar + 4);
                    float4 v2 = *(const float4*)(ar + 8);
                    float4 v3 = *(const float4*)(ar + 12);
                    pa0[0] = f2bf2(v0.x, v0.y); pa0[1] = f2bf2(v0.z, v0.w);
                    pa0[2] = f2bf2(v1.x, v1.y); pa0[3] = f2bf2(v1.z, v1.w);
                    pa1[0] = f2bf2(v2.x, v2.y); pa1[1] = f2bf2(v2.z, v2.w);
                    pa1[2] = f2bf2(v3.x, v3.y); pa1[3] = f2bf2(v3.z, v3.w);
                }
                *(u32x4*)&As[r][cq]     = pa0;
                *(u32x4*)&As[r][cq + 8] = pa1;
            }
            {
                int gc = bn + r;
                u32x4 pw0 = {}, pw1 = {};
                if (gc < N) {
                    const float* wr = W + (size_t)gc * K + k0 + cq;
                    float4 v0 = *(const float4*)(wr);
                    float4 v1 = *(const float4*)(wr + 4);
                    float4 v2 = *(const float4*)(wr + 8);
                    float4 v3 = *(const float4*)(wr + 12);
                    pw0[0] = f2bf2(v0.x, v0.y); pw0[1] = f2bf2(v0.z, v0.w);
                    pw0[2] = f2bf2(v1.x, v1.y); pw0[3] = f2bf2(v1.z, v1.w);
                    pw1[0] = f2bf2(v2.x, v2.y); pw1[1] = f2bf2(v2.z, v2.w);
                    pw1[2] = f2bf2(v3.x, v3.y); pw1[3] = f2bf2(v3.z, v3.w);
                }
                *(u32x4*)&Ws[r][cq]     = pw0;
                *(u32x4*)&Ws[r][cq + 8] = pw1;
            }
            __syncthreads();
            #pragma unroll
            for (int kc = 0; kc < 2; ++kc) {
                us8v af0 = *(const us8v*)&As[wm + l15][kc * 32 + lg * 8];
                us8v af1 = *(const us8v*)&As[wm + 16 + l15][kc * 32 + lg * 8];
                us8v wf0 = *(const us8v*)&Ws[wn + l15][kc * 32 + lg * 8];
                us8v wf1 = *(const us8v*)&Ws[wn + 16 + l15][kc * 32 + lg * 8];
                acc00 = mfma_bf16(af0, wf0, acc00);
                acc01 = mfma_bf16(af0, wf1, acc01);
                acc10 = mfma_bf16(af1, wf0, acc10);
                acc11 = mfma_bf16(af1, wf1, acc11);
            }
            __syncthreads();
        }
        const float* bias = ge.bias;
        const float* res  = ge.res;
        f32x4v accs[2][2] = { { acc00, acc01 }, { acc10, acc11 } };
        #pragma unroll
        for (int fi = 0; fi < 2; ++fi) {
            #pragma unroll
            for (int fj = 0; fj < 2; ++fj) {
                int col = bn + wn + fj * 16 + l15;
                if (col >= N) continue;
                float bv = bias ? bias[col] : 0.f;
                #pragma unroll
                for (int rr = 0; rr < 4; ++rr) {
                    int row = bm + wm + fi * 16 + lg * 4 + rr;
                    if (row >= M) continue;
                    float v = accs[fi][fj][rr] + bv;
                    if (dogelu) v = 0.5f * v * (1.f + erff(v * 0.70710678118654752f));
                    if (OBF) {
                        ((unsigned short*)ge.out)[(size_t)row * N + col] = f2bf(v);
                    } else {
                        if (res) v += res[(size_t)row * N + col];
                        ((float*)ge.out)[(size_t)row * N + col] = v;
                    }
                }
            }
        }
        if (mt + 1 < mtiles) __syncthreads();
    }
}

// ========================================================================
// Attention scores via MFMA: S[z][i][j] = scale * Q[i,:]·K[j,:]  (z = b*12+h)
// ========================================================================
template <int QBF>
__global__ __launch_bounds__(256)
void k_scores(const void* __restrict__ qv, const float* __restrict__ kk,
              float* __restrict__ sws, float* __restrict__ cqk,
              int Nk, int sld, int selfmask, int kPerB)
{
    constexpr int LD = 72;
    __shared__ unsigned short As[64][LD];
    __shared__ unsigned short Ks[64][LD];
    int z = blockIdx.z, b = z / kH, h = z % kH;
    int bm = blockIdx.x * 64, bn = blockIdx.y * 64;
    const float* kbase = kk + (kPerB ? (size_t)b * kMC * kD : 0) + (size_t)h * kDH;

    int tid = threadIdx.x;
    int r = tid >> 2, c0 = (tid & 3) * 16;
    {
        if (QBF) {
            const unsigned short* q = (const unsigned short*)qv;
            const unsigned short* qr =
                q + (size_t)(b * kMC + bm + r) * kD + h * kDH + c0;
            *(us8v*)&As[r][c0]     = *(const us8v*)qr;
            *(us8v*)&As[r][c0 + 8] = *(const us8v*)(qr + 8);
        } else {
            const float* q = (const float*)qv;
            const float* qr = q + (size_t)(b * kMC + bm + r) * kD + h * kDH + c0;
            float4 v0 = *(const float4*)(qr);
            float4 v1 = *(const float4*)(qr + 4);
            float4 v2 = *(const float4*)(qr + 8);
            float4 v3 = *(const float4*)(qr + 12);
            u32x4 p0, p1;
            p0[0] = f2bf2(v0.x, v0.y); p0[1] = f2bf2(v0.z, v0.w);
            p0[2] = f2bf2(v1.x, v1.y); p0[3] = f2bf2(v1.z, v1.w);
            p1[0] = f2bf2(v2.x, v2.y); p1[1] = f2bf2(v2.z, v2.w);
            p1[2] = f2bf2(v3.x, v3.y); p1[3] = f2bf2(v3.z, v3.w);
            *(u32x4*)&As[r][c0]     = p0;
            *(u32x4*)&As[r][c0 + 8] = p1;
        }
        int gk = bn + r;
        if (gk < Nk) {
            const float* kr = kbase + (size_t)gk * kD + c0;
            float4 v0 = *(const float4*)(kr);
            float4 v1 = *(const float4*)(kr + 4);
            float4 v2 = *(const float4*)(kr + 8);
            float4 v3 = *(const float4*)(kr + 12);
            u32x4 p0, p1;
            p0[0] = f2bf2(v0.x, v0.y); p0[1] = f2bf2(v0.z, v0.w);
            p0[2] = f2bf2(v1.x, v1.y); p0[3] = f2bf2(v1.z, v1.w);
            p1[0] = f2bf2(v2.x, v2.y); p1[1] = f2bf2(v2.z, v2.w);
            p1[2] = f2bf2(v3.x, v3.y); p1[3] = f2bf2(v3.z, v3.w);
            *(u32x4*)&Ks[r][c0]     = p0;
            *(u32x4*)&Ks[r][c0 + 8] = p1;
        } else {
            u32x4 zz = {};
            *(u32x4*)&Ks[r][c0]     = zz;
            *(u32x4*)&Ks[r][c0 + 8] = zz;
        }
    }
    __syncthreads();

    int wid = tid >> 6, lane = tid & 63;
    int wm = (wid >> 1) * 32, wn = (wid & 1) * 32;
    int l15 = lane & 15, lg = lane >> 4;

    f32x4v acc[2][2] = {};
    #pragma unroll
    for (int kc = 0; kc < 2; ++kc) {
        us8v a0 = *(const us8v*)&As[wm + l15][kc * 32 + lg * 8];
        us8v a1 = *(const us8v*)&As[wm + 16 + l15][kc * 32 + lg * 8];
        us8v b0 = *(const us8v*)&Ks[wn + l15][kc * 32 + lg * 8];
        us8v b1 = *(const us8v*)&Ks[wn + 16 + l15][kc * 32 + lg * 8];
        acc[0][0] = mfma_bf16(a0, b0, acc[0][0]);
        acc[0][1] = mfma_bf16(a0, b1, acc[0][1]);
        acc[1][0] = mfma_bf16(a1, b0, acc[1][0]);
        acc[1][1] = mfma_bf16(a1, b1, acc[1][1]);
    }

    #pragma unroll
    for (int fm = 0; fm < 2; ++fm) {
        #pragma unroll
        for (int fn = 0; fn < 2; ++fn) {
            int gj = bn + wn + fn * 16 + l15;
            if (gj >= Nk) continue;
            #pragma unroll
            for (int rr = 0; rr < 4; ++rr) {
                int gi = bm + wm + fm * 16 + lg * 4 + rr;
                float val = acc[fm][fn][rr] * kScale;
                if (cqk && gi < kT)
                    cqk[(((size_t)(b * kH + h)) * kT + gi) * kSA + gj] = val;
                if (selfmask && (gj > gi || gj >= kT)) val = -1e30f;
                sws[((size_t)z * kMC + gi) * sld + gj] = val;
            }
        }
    }
}

// ========================================================================
// Softmax + PV: block = 4 q-rows of one (b,h); wave w owns row i0+w.
// ========================================================================
__global__ __launch_bounds__(256)
void k_smpv(const float* __restrict__ sws, const float* __restrict__ vv,
            unsigned short* __restrict__ o, int Nk, int sld, int vPerB)
{
    __shared__ float p[4][kSLDc];
    __shared__ float inv[4];
    int z = blockIdx.y, b = z / kH, h = z % kH;
    int i0 = blockIdx.x * 4;
    int t = threadIdx.x, w = t >> 6, ln = t & 63;

    const float* srow = sws + ((size_t)z * kMC + i0 + w) * sld;
    float mx = -3e38f;
    for (int j = ln; j < Nk; j += 64) mx = fmaxf(mx, srow[j]);
    for (int off = 32; off > 0; off >>= 1) mx = fmaxf(mx, __shfl_xor(mx, off));
    float sum = 0.f;
    for (int j = ln; j < Nk; j += 64) {
        float e = expf(srow[j] - mx);
        p[w][j] = e;
        sum += e;
    }
    for (int off = 32; off > 0; off >>= 1) sum += __shfl_xor(sum, off);
    if (ln == 0) inv[w] = 1.f / sum;
    __syncthreads();

    int jj = ln >> 4, d4 = ln & 15;
    const float* vbase = vv + (vPerB ? (size_t)b * kMC * kD : 0)
                            + (size_t)h * kDH + d4 * 4;
    float ax = 0.f, ay = 0.f, az = 0.f, aw = 0.f;
    for (int j = 0; j < Nk; j += 4) {
        float pv = p[w][j + jj];
        float4 v = *(const float4*)(vbase + (size_t)(j + jj) * kD);
        ax += pv * v.x; ay += pv * v.y; az += pv * v.z; aw += pv * v.w;
    }
    #pragma unroll
    for (int off = 16; off <= 32; off <<= 1) {
        ax += __shfl_xor(ax, off);
        ay += __shfl_xor(ay, off);
        az += __shfl_xor(az, off);
        aw += __shfl_xor(aw, off);
    }
    if (jj == 0) {
        float iv = inv[w];
        us4v pk;
        pk[0] = f2bf(ax * iv); pk[1] = f2bf(ay * iv);
        pk[2] = f2bf(az * iv); pk[3] = f2bf(aw * iv);
        *(us4v*)&o[(size_t)(b * kMC + i0 + w) * kD + h * kDH + d4 * 4] = pk;
    }
}

// ========================================================================
extern "C" void kernel_launch(void* const* d_in, const int* in_sizes, int n_in,
                              void* d_out, int out_size, void* d_ws, size_t ws_size,
                              hipStream_t stream)
{
    const int*   x   = (const int*)  d_in[0];
    const float* xa  = (const float*)d_in[1];
    const float* tok = (const float*)d_in[4];
    const float* pos = (const float*)d_in[5];
    const float* attn_ln_g  = (const float*)d_in[6];
    const float* attn_ln_b  = (const float*)d_in[7];
    const float* attn_q_w   = (const float*)d_in[8];
    const float* attn_q_b   = (const float*)d_in[9];
    const float* attn_k_w   = (const float*)d_in[10];
    const float* attn_v_w   = (const float*)d_in[11];
    const float* attn_v_b   = (const float*)d_in[12];
    const float* attn_o_w   = (const float*)d_in[13];
    const float* attn_o_b   = (const float*)d_in[14];
    const float* cross_ln_g = (const float*)d_in[15];
    const float* cross_ln_b = (const float*)d_in[16];
    const float* cross_q_w  = (const float*)d_in[17];
    const float* cross_q_b  = (const float*)d_in[18];
    const float* cross_k_w  = (const float*)d_in[19];
    const float* cross_v_w  = (const float*)d_in[20];
    const float* cross_v_b  = (const float*)d_in[21];
    const float* cross_o_w  = (const float*)d_in[22];
    const float* cross_o_b  = (const float*)d_in[23];
    const float* mlp_ln_g   = (const float*)d_in[24];
    const float* mlp_ln_b   = (const float*)d_in[25];
    const float* mlp_w1     = (const float*)d_in[26];
    const float* mlp_b1     = (const float*)d_in[27];
    const float* mlp_w2     = (const float*)d_in[28];
    const float* mlp_b2     = (const float*)d_in[29];
    const float* ln_g       = (const float*)d_in[30];
    const float* ln_b       = (const float*)d_in[31];

    float* out = (float*)d_out;
    float* h    = (float*)d_ws;                          // 512*768 f32
    float* qws  = h   + (size_t)kR * kD;                 // 512*768 f32 (self q)
    float* sS   = qws + (size_t)kR * kD;                 // 24*256*1504 f32
    unsigned short* y16   = (unsigned short*)(sS + (size_t)kB * kH * kMC * kSLDc);
    unsigned short* qb16  = y16  + (size_t)kR * kD;      // cross q bf16
    unsigned short* o16   = qb16 + (size_t)kR * kD;      // attn out bf16
    unsigned short* hid16 = o16  + (size_t)kR * kD;      // MLP hidden bf16
    unsigned short* yF16  = hid16 + (size_t)kR * 4 * kD; // final LN bf16

    k_embed<<<kB * kMC * kD / 256, 256, 0, stream>>>(x, tok, pos, h);

    // all cross K/V projections (layer-invariant input xa) in ONE launch
    {
        GBatch gc{};
        for (int l = 0; l < kL; ++l) {
            gc.e[2 * l]     = { cross_k_w + (size_t)l * kD * kD, nullptr, nullptr,
                                out + OFF_CKV + (size_t)(2 * l) * kSA * kD };
            gc.e[2 * l + 1] = { cross_v_w + (size_t)l * kD * kD, cross_v_b + (size_t)l * kD,
                                nullptr,
                                out + OFF_CKV + (size_t)(2 * l + 1) * kSA * kD };
        }
        gemm_t<0, 0><<<dim3((kSA + 63) / 64, kD / 64, 2 * kL), 256, 0, stream>>>(
            xa, gc, kSA, kD, kD, 0, 1);
    }

    for (int l = 0; l < kL; ++l) {
        size_t dd = (size_t)l * kD * kD;
        float* kbuf  = out + OFF_MKV + (size_t)(2 * l)     * kB * kMC * kD;
        float* vbuf  = out + OFF_MKV + (size_t)(2 * l + 1) * kB * kMC * kD;
        float* ckbuf = out + OFF_CKV + (size_t)(2 * l)     * kSA * kD;
        float* cvbuf = out + OFF_CKV + (size_t)(2 * l + 1) * kSA * kD;
        float* cqk   = out + OFF_CQK + (size_t)l * kB * kH * kT * kSA;

        // --- self attention ---
        k_ln<<<kR, 256, 0, stream>>>(h, attn_ln_g + l * kD, attn_ln_b + l * kD, y16);
        {
            GBatch g3{};
            g3.e[0] = { attn_q_w + dd, attn_q_b + (size_t)l * kD, nullptr, qws };
            g3.e[1] = { attn_k_w + dd, nullptr,                   nullptr, kbuf };
            g3.e[2] = { attn_v_w + dd, attn_v_b + (size_t)l * kD, nullptr, vbuf };
            gemm_t<1, 0><<<dim3(kR / 64, kD / 64, 3), 256, 0, stream>>>(
                y16, g3, kR, kD, kD, 0, 1);
        }
        k_scores<0><<<dim3(kMC / 64, kMC / 64, kB * kH), 256, 0, stream>>>(
            qws, kbuf, sS, nullptr, kMC, kMC, 1, 1);
        k_smpv<<<dim3(kMC / 4, kB * kH), 256, 0, stream>>>(sS, vbuf, o16, kMC, kMC, 1);
        {
            GBatch g1{};
            g1.e[0] = { attn_o_w + dd, attn_o_b + (size_t)l * kD, h, h };
            gemm_t<1, 0><<<dim3(kR / 64, kD / 64, 1), 256, 0, stream>>>(
                o16, g1, kR, kD, kD, 0, 1);
        }

        // --- cross attention ---
        k_ln<<<kR, 256, 0, stream>>>(h, cross_ln_g + l * kD, cross_ln_b + l * kD, y16);
        {
            GBatch g1{};
            g1.e[0] = { cross_q_w + dd, cross_q_b + (size_t)l * kD, nullptr, qb16 };
            gemm_t<1, 1><<<dim3(kR / 64, kD / 64, 1), 256, 0, stream>>>(
                y16, g1, kR, kD, kD, 0, 1);
        }
        k_scores<1><<<dim3(kMC / 64, (kSA + 63) / 64, kB * kH), 256, 0, stream>>>(
            qb16, ckbuf, sS, cqk, kSA, kSLDc, 0, 0);
        k_smpv<<<dim3(kMC / 4, kB * kH), 256, 0, stream>>>(sS, cvbuf, o16, kSA, kSLDc, 0);
        {
            GBatch g1{};
            g1.e[0] = { cross_o_w + dd, cross_o_b + (size_t)l * kD, h, h };
            gemm_t<1, 0><<<dim3(kR / 64, kD / 64, 1), 256, 0, stream>>>(
                o16, g1, kR, kD, kD, 0, 1);
        }

        // --- MLP ---
        k_ln<<<kR, 256, 0, stream>>>(h, mlp_ln_g + l * kD, mlp_ln_b + l * kD, y16);
        {
            GBatch g1{};
            g1.e[0] = { mlp_w1 + (size_t)l * 4 * kD * kD, mlp_b1 + (size_t)l * 4 * kD,
                        nullptr, hid16 };
            gemm_t<1, 1><<<dim3(kR / 64, 4 * kD / 64, 1), 256, 0, stream>>>(
                y16, g1, kR, 4 * kD, kD, 1, 1);
        }
        {
            GBatch g1{};
            g1.e[0] = { mlp_w2 + (size_t)l * 4 * kD * kD, mlp_b2 + (size_t)l * kD, h, h };
            gemm_t<1, 0><<<dim3(kR / 64, kD / 64, 1), 256, 0, stream>>>(
                hid16, g1, kR, kD, 4 * kD, 0, 1);
        }
    }

    k_finalln<<<kB * kT, 256, 0, stream>>>(h, ln_g, ln_b, yF16);
    {
        // logits: 6 in-block M-tiles so each block streams tok_emb once
        GBatch g1{};
        g1.e[0] = { tok, nullptr, nullptr, out };
        gemm_t<1, 0><<<dim3(1, (kV + 63) / 64, 1), 256, 0, stream>>>(
            yF16, g1, kB * kT, kV, kD, 0, 6);
    }
}

// Round 8
// 4187.402 us; speedup vs baseline: 5.5682x; 1.0384x over previous
//
#include <hip/hip_runtime.h>
#include <math.h>

// ---- problem constants --------------------------------------------------
constexpr int kL = 12, kD = 768, kH = 12, kV = 51865, kSA = 1500;
constexpr int kB = 2, kT = 192, kMC = 256, kDH = 64;
constexpr float kScale = 0.125f;      // DH^-0.5
constexpr float kEps = 1e-5f;
constexpr int kR = kB * kMC;          // 512 rows through the layer stack
constexpr int kSLDc = 1504;           // cross score row stride (pad)

// ---- d_out layout (flat float32, reference return order) ---------------
constexpr size_t SZ_LOGITS = (size_t)kB * kT * kV;
constexpr size_t SZ_CQK    = (size_t)kL * kB * kH * kT * kSA;
constexpr size_t SZ_MKV    = (size_t)2 * kL * kB * kMC * kD;
constexpr size_t OFF_CQK = SZ_LOGITS;
constexpr size_t OFF_MKV = OFF_CQK + SZ_CQK;
constexpr size_t OFF_CKV = OFF_MKV + SZ_MKV;

typedef float f32x4v __attribute__((ext_vector_type(4)));
typedef unsigned short us8v __attribute__((ext_vector_type(8)));
typedef unsigned short us4v __attribute__((ext_vector_type(4)));
typedef unsigned int   u32x4 __attribute__((ext_vector_type(4)));

static __device__ __forceinline__ unsigned short f2bf(float f) {
    unsigned int u = __float_as_uint(f);
    u += 0x7fffu + ((u >> 16) & 1u);          // round-to-nearest-even
    return (unsigned short)(u >> 16);
}

// packed f32x2 -> bf16x2 (RNE), low half from `lo`
static __device__ __forceinline__ unsigned int f2bf2(float lo, float hi) {
    unsigned int r;
    asm("v_cvt_pk_bf16_f32 %0, %1, %2" : "=v"(r) : "v"(lo), "v"(hi));
    return r;
}

static __device__ __forceinline__ f32x4v mfma_bf16(us8v a, us8v b, f32x4v c) {
    asm("v_mfma_f32_16x16x32_bf16 %0, %1, %2, %0" : "+v"(c) : "v"(a), "v"(b));
    return c;
}

// ========================================================================
// embedding
// ========================================================================
__global__ void k_embed(const int* __restrict__ x, const float* __restrict__ tok,
                        const float* __restrict__ pos, float* __restrict__ h)
{
    int idx = blockIdx.x * 256 + threadIdx.x;
    int d = idx % kD;
    int t = (idx / kD) % kMC;
    int b = idx / (kD * kMC);
    float v = 0.f;
    if (t < kT) {
        int tokid = x[b * kT + t];
        v = tok[(size_t)tokid * kD + d] + pos[(size_t)t * kD + d];
    }
    h[idx] = v;
}

// ========================================================================
// LayerNorm (256 thr per row of 768) -> bf16 output
// ========================================================================
__global__ void k_ln(const float* __restrict__ in, const float* __restrict__ g,
                     const float* __restrict__ bb, unsigned short* __restrict__ out)
{
    int r = blockIdx.x;
    const float* xr = in + (size_t)r * kD;
    int t = threadIdx.x;
    float x0 = xr[t], x1 = xr[t + 256], x2 = xr[t + 512];
    float s  = x0 + x1 + x2;
    float sq = x0 * x0 + x1 * x1 + x2 * x2;
    __shared__ float red[8];
    for (int o = 32; o > 0; o >>= 1) { s += __shfl_down(s, o); sq += __shfl_down(sq, o); }
    int w = t >> 6;
    if ((t & 63) == 0) { red[w] = s; red[4 + w] = sq; }
    __syncthreads();
    s  = red[0] + red[1] + red[2] + red[3];
    sq = red[4] + red[5] + red[6] + red[7];
    float m   = s * (1.f / kD);
    float var = sq * (1.f / kD) - m * m;
    float rs  = rsqrtf(var + kEps);
    unsigned short* orow = out + (size_t)r * kD;
    orow[t]       = f2bf((x0 - m) * rs * g[t]       + bb[t]);
    orow[t + 256] = f2bf((x1 - m) * rs * g[t + 256] + bb[t + 256]);
    orow[t + 512] = f2bf((x2 - m) * rs * g[t + 512] + bb[t + 512]);
}

__global__ void k_finalln(const float* __restrict__ h, const float* __restrict__ g,
                          const float* __restrict__ bb, unsigned short* __restrict__ out)
{
    int r = blockIdx.x;                 // 0..kB*kT
    int b = r / kT, tt = r % kT;
    const float* xr = h + (size_t)(b * kMC + tt) * kD;
    int t = threadIdx.x;
    float x0 = xr[t], x1 = xr[t + 256], x2 = xr[t + 512];
    float s  = x0 + x1 + x2;
    float sq = x0 * x0 + x1 * x1 + x2 * x2;
    __shared__ float red[8];
    for (int o = 32; o > 0; o >>= 1) { s += __shfl_down(s, o); sq += __shfl_down(sq, o); }
    int w = t >> 6;
    if ((t & 63) == 0) { red[w] = s; red[4 + w] = sq; }
    __syncthreads();
    s  = red[0] + red[1] + red[2] + red[3];
    sq = red[4] + red[5] + red[6] + red[7];
    float m   = s * (1.f / kD);
    float var = sq * (1.f / kD) - m * m;
    float rs  = rsqrtf(var + kEps);
    unsigned short* orow = out + (size_t)r * kD;
    orow[t]       = f2bf((x0 - m) * rs * g[t]       + bb[t]);
    orow[t + 256] = f2bf((x1 - m) * rs * g[t + 256] + bb[t + 256]);
    orow[t + 512] = f2bf((x2 - m) * rs * g[t + 512] + bb[t + 512]);
}

// ========================================================================
// bf16-MFMA GEMM, z-batched via pointer table. BK=64, BM=BN=64.
// ========================================================================
struct GEntry { const float* W; const float* bias; const float* res; void* out; };
struct GBatch { GEntry e[24]; };

template <int ABF, int OBF>
__global__ __launch_bounds__(256)
void gemm_t(const void* __restrict__ Av, GBatch gb, int M, int N, int K,
            int dogelu, int mtiles)
{
    constexpr int LD = 72;
    __shared__ unsigned short As[64][LD];
    __shared__ unsigned short Ws[64][LD];
    const GEntry ge = gb.e[blockIdx.z];
    const float* __restrict__ W = ge.W;
    int bn = blockIdx.y * 64;
    int tid = threadIdx.x;
    int wid = tid >> 6, lane = tid & 63;
    int wm = (wid >> 1) * 32, wn = (wid & 1) * 32;
    int l15 = lane & 15, lg = lane >> 4;
    int r = tid >> 2, cq = (tid & 3) * 16;

    for (int mt = 0; mt < mtiles; ++mt) {
        int bm = (blockIdx.x * mtiles + mt) * 64;
        f32x4v acc00 = {}, acc01 = {}, acc10 = {}, acc11 = {};
        for (int k0 = 0; k0 < K; k0 += 64) {
            int gr = bm + r;
            if (ABF) {
                const unsigned short* A = (const unsigned short*)Av;
                us8v v0 = {}, v1 = {};
                if (gr < M) {
                    const unsigned short* ar = A + (size_t)gr * K + k0 + cq;
                    v0 = *(const us8v*)ar;
                    v1 = *(const us8v*)(ar + 8);
                }
                *(us8v*)&As[r][cq]     = v0;
                *(us8v*)&As[r][cq + 8] = v1;
            } else {
                const float* A = (const float*)Av;
                u32x4 pa0 = {}, pa1 = {};
                if (gr < M) {
                    const float* ar = A + (size_t)gr * K + k0 + cq;
                    float4 v0 = *(const float4*)(ar);
                    float4 v1 = *(const float4*)(ar + 4);
                    float4 v2 = *(const float4*)(ar + 8);
                    float4 v3 = *(const float4*)(ar + 12);
                    pa0[0] = f2bf2(v0.x, v0.y); pa0[1] = f2bf2(v0.z, v0.w);
                    pa0[2] = f2bf2(v1.x, v1.y); pa0[3] = f2bf2(v1.z, v1.w);
                    pa1[0] = f2bf2(v2.x, v2.y); pa1[1] = f2bf2(v2.z, v2.w);
                    pa1[2] = f2bf2(v3.x, v3.y); pa1[3] = f2bf2(v3.z, v3.w);
                }
                *(u32x4*)&As[r][cq]     = pa0;
                *(u32x4*)&As[r][cq + 8] = pa1;
            }
            {
                int gc = bn + r;
                u32x4 pw0 = {}, pw1 = {};
                if (gc < N) {
                    const float* wr = W + (size_t)gc * K + k0 + cq;
                    float4 v0 = *(const float4*)(wr);
                    float4 v1 = *(const float4*)(wr + 4);
                    float4 v2 = *(const float4*)(wr + 8);
                    float4 v3 = *(const float4*)(wr + 12);
                    pw0[0] = f2bf2(v0.x, v0.y); pw0[1] = f2bf2(v0.z, v0.w);
                    pw0[2] = f2bf2(v1.x, v1.y); pw0[3] = f2bf2(v1.z, v1.w);
                    pw1[0] = f2bf2(v2.x, v2.y); pw1[1] = f2bf2(v2.z, v2.w);
                    pw1[2] = f2bf2(v3.x, v3.y); pw1[3] = f2bf2(v3.z, v3.w);
                }
                *(u32x4*)&Ws[r][cq]     = pw0;
                *(u32x4*)&Ws[r][cq + 8] = pw1;
            }
            __syncthreads();
            #pragma unroll
            for (int kc = 0; kc < 2; ++kc) {
                us8v af0 = *(const us8v*)&As[wm + l15][kc * 32 + lg * 8];
                us8v af1 = *(const us8v*)&As[wm + 16 + l15][kc * 32 + lg * 8];
                us8v wf0 = *(const us8v*)&Ws[wn + l15][kc * 32 + lg * 8];
                us8v wf1 = *(const us8v*)&Ws[wn + 16 + l15][kc * 32 + lg * 8];
                acc00 = mfma_bf16(af0, wf0, acc00);
                acc01 = mfma_bf16(af0, wf1, acc01);
                acc10 = mfma_bf16(af1, wf0, acc10);
                acc11 = mfma_bf16(af1, wf1, acc11);
            }
            __syncthreads();
        }
        const float* bias = ge.bias;
        const float* res  = ge.res;
        f32x4v accs[2][2] = { { acc00, acc01 }, { acc10, acc11 } };
        #pragma unroll
        for (int fi = 0; fi < 2; ++fi) {
            #pragma unroll
            for (int fj = 0; fj < 2; ++fj) {
                int col = bn + wn + fj * 16 + l15;
                if (col >= N) continue;
                float bv = bias ? bias[col] : 0.f;
                #pragma unroll
                for (int rr = 0; rr < 4; ++rr) {
                    int row = bm + wm + fi * 16 + lg * 4 + rr;
                    if (row >= M) continue;
                    float v = accs[fi][fj][rr] + bv;
                    if (dogelu) v = 0.5f * v * (1.f + erff(v * 0.70710678118654752f));
                    if (OBF) {
                        ((unsigned short*)ge.out)[(size_t)row * N + col] = f2bf(v);
                    } else {
                        if (res) v += res[(size_t)row * N + col];
                        ((float*)ge.out)[(size_t)row * N + col] = v;
                    }
                }
            }
        }
        if (mt + 1 < mtiles) __syncthreads();
    }
}

// ========================================================================
// Attention scores via MFMA (unchanged, passing)
// ========================================================================
template <int QBF>
__global__ __launch_bounds__(256)
void k_scores(const void* __restrict__ qv, const float* __restrict__ kk,
              float* __restrict__ sws, float* __restrict__ cqk,
              int Nk, int sld, int selfmask, int kPerB)
{
    constexpr int LD = 72;
    __shared__ unsigned short As[64][LD];
    __shared__ unsigned short Ks[64][LD];
    int z = blockIdx.z, b = z / kH, h = z % kH;
    int bm = blockIdx.x * 64, bn = blockIdx.y * 64;
    const float* kbase = kk + (kPerB ? (size_t)b * kMC * kD : 0) + (size_t)h * kDH;

    int tid = threadIdx.x;
    int r = tid >> 2, c0 = (tid & 3) * 16;
    {
        if (QBF) {
            const unsigned short* q = (const unsigned short*)qv;
            const unsigned short* qr =
                q + (size_t)(b * kMC + bm + r) * kD + h * kDH + c0;
            *(us8v*)&As[r][c0]     = *(const us8v*)qr;
            *(us8v*)&As[r][c0 + 8] = *(const us8v*)(qr + 8);
        } else {
            const float* q = (const float*)qv;
            const float* qr = q + (size_t)(b * kMC + bm + r) * kD + h * kDH + c0;
            float4 v0 = *(const float4*)(qr);
            float4 v1 = *(const float4*)(qr + 4);
            float4 v2 = *(const float4*)(qr + 8);
            float4 v3 = *(const float4*)(qr + 12);
            u32x4 p0, p1;
            p0[0] = f2bf2(v0.x, v0.y); p0[1] = f2bf2(v0.z, v0.w);
            p0[2] = f2bf2(v1.x, v1.y); p0[3] = f2bf2(v1.z, v1.w);
            p1[0] = f2bf2(v2.x, v2.y); p1[1] = f2bf2(v2.z, v2.w);
            p1[2] = f2bf2(v3.x, v3.y); p1[3] = f2bf2(v3.z, v3.w);
            *(u32x4*)&As[r][c0]     = p0;
            *(u32x4*)&As[r][c0 + 8] = p1;
        }
        int gk = bn + r;
        if (gk < Nk) {
            const float* kr = kbase + (size_t)gk * kD + c0;
            float4 v0 = *(const float4*)(kr);
            float4 v1 = *(const float4*)(kr + 4);
            float4 v2 = *(const float4*)(kr + 8);
            float4 v3 = *(const float4*)(kr + 12);
            u32x4 p0, p1;
            p0[0] = f2bf2(v0.x, v0.y); p0[1] = f2bf2(v0.z, v0.w);
            p0[2] = f2bf2(v1.x, v1.y); p0[3] = f2bf2(v1.z, v1.w);
            p1[0] = f2bf2(v2.x, v2.y); p1[1] = f2bf2(v2.z, v2.w);
            p1[2] = f2bf2(v3.x, v3.y); p1[3] = f2bf2(v3.z, v3.w);
            *(u32x4*)&Ks[r][c0]     = p0;
            *(u32x4*)&Ks[r][c0 + 8] = p1;
        } else {
            u32x4 zz = {};
            *(u32x4*)&Ks[r][c0]     = zz;
            *(u32x4*)&Ks[r][c0 + 8] = zz;
        }
    }
    __syncthreads();

    int wid = tid >> 6, lane = tid & 63;
    int wm = (wid >> 1) * 32, wn = (wid & 1) * 32;
    int l15 = lane & 15, lg = lane >> 4;

    f32x4v acc[2][2] = {};
    #pragma unroll
    for (int kc = 0; kc < 2; ++kc) {
        us8v a0 = *(const us8v*)&As[wm + l15][kc * 32 + lg * 8];
        us8v a1 = *(const us8v*)&As[wm + 16 + l15][kc * 32 + lg * 8];
        us8v b0 = *(const us8v*)&Ks[wn + l15][kc * 32 + lg * 8];
        us8v b1 = *(const us8v*)&Ks[wn + 16 + l15][kc * 32 + lg * 8];
        acc[0][0] = mfma_bf16(a0, b0, acc[0][0]);
        acc[0][1] = mfma_bf16(a0, b1, acc[0][1]);
        acc[1][0] = mfma_bf16(a1, b0, acc[1][0]);
        acc[1][1] = mfma_bf16(a1, b1, acc[1][1]);
    }

    #pragma unroll
    for (int fm = 0; fm < 2; ++fm) {
        #pragma unroll
        for (int fn = 0; fn < 2; ++fn) {
            int gj = bn + wn + fn * 16 + l15;
            if (gj >= Nk) continue;
            #pragma unroll
            for (int rr = 0; rr < 4; ++rr) {
                int gi = bm + wm + fm * 16 + lg * 4 + rr;
                float val = acc[fm][fn][rr] * kScale;
                if (cqk && gi < kT)
                    cqk[(((size_t)(b * kH + h)) * kT + gi) * kSA + gj] = val;
                if (selfmask && (gj > gi || gj >= kT)) val = -1e30f;
                sws[((size_t)z * kMC + gi) * sld + gj] = val;
            }
        }
    }
}

// ========================================================================
// Softmax + PV via MFMA. Block = 16 q-rows of one z (grid (kMC/16, 24)).
// Pass 1: per-row max & 1/sum from global scores (proven k_smpv pattern).
// Pass 2: chunks of 128 keys: stage P=exp(s-mx) bf16 [16][136] and V^T
// bf16 [64][136]; wave wid computes dims [wid*16,wid*16+16) with 4 MFMAs
// per chunk (proven gemm_t fragment pattern). ~22 KB LDS.
// ========================================================================
constexpr int kCH  = 128;   // key chunk
constexpr int kLDK = 136;   // bf16 k-stride (136*2=272 B, 16B-aligned rows)
__global__ __launch_bounds__(256)
void k_pv(const float* __restrict__ sws, const float* __restrict__ vv,
          unsigned short* __restrict__ o, int Nk, int sld, int vPerB)
{
    __shared__ unsigned short Pb[16][kLDK];
    __shared__ unsigned short Vt[64][kLDK];
    __shared__ float smx[16], sinv[16];
    int z = blockIdx.y, b = z / kH, h = z % kH;
    int i0 = blockIdx.x * 16;
    int t = threadIdx.x, wid = t >> 6, lane = t & 63;
    int l15 = lane & 15, lg = lane >> 4;
    const float* vbase = vv + (vPerB ? (size_t)b * kMC * kD : 0) + (size_t)h * kDH;

    // ---- pass 1: row max & inv-sum (wave handles rows wid, wid+4, ...) ----
    for (int r = wid; r < 16; r += 4) {
        const float* srow = sws + ((size_t)z * kMC + i0 + r) * sld;
        float mx = -3e38f;
        for (int j = lane; j < Nk; j += 64) mx = fmaxf(mx, srow[j]);
        for (int off = 32; off > 0; off >>= 1) mx = fmaxf(mx, __shfl_xor(mx, off));
        float sum = 0.f;
        for (int j = lane; j < Nk; j += 64) sum += expf(srow[j] - mx);
        for (int off = 32; off > 0; off >>= 1) sum += __shfl_xor(sum, off);
        if (lane == 0) { smx[r] = mx; sinv[r] = 1.f / sum; }
    }
    __syncthreads();

    // ---- pass 2: chunked MFMA PV ----
    int pr = t >> 4;                 // P-stage row 0..15 (also exp row)
    int jb = (t & 15) * 8;           // P-stage key base within chunk
    const float* srow = sws + ((size_t)z * kMC + i0 + pr) * sld;
    float mxv = smx[pr];

    f32x4v acc = {};
    for (int k0 = 0; k0 < Nk; k0 += kCH) {
        // stage V^T: 4 u-steps, each thread: 2 adjacent key rows x 4 dims
        #pragma unroll
        for (int u = 0; u < 4; ++u) {
            int flat = t + u * 256;              // 0..1023
            int kr = (flat >> 4) * 2;            // even key within chunk
            int c4 = flat & 15;                  // dim group (4 dims)
            float4 va = {0,0,0,0}, vb2 = {0,0,0,0};
            if (k0 + kr < Nk)
                va = *(const float4*)(vbase + (size_t)(k0 + kr) * kD + c4 * 4);
            if (k0 + kr + 1 < Nk)
                vb2 = *(const float4*)(vbase + (size_t)(k0 + kr + 1) * kD + c4 * 4);
            *(unsigned int*)&Vt[c4 * 4 + 0][kr] = f2bf2(va.x, vb2.x);
            *(unsigned int*)&Vt[c4 * 4 + 1][kr] = f2bf2(va.y, vb2.y);
            *(unsigned int*)&Vt[c4 * 4 + 2][kr] = f2bf2(va.z, vb2.z);
            *(unsigned int*)&Vt[c4 * 4 + 3][kr] = f2bf2(va.w, vb2.w);
        }
        // stage P row pr, keys jb..jb+7
        #pragma unroll
        for (int u = 0; u < 8; u += 2) {
            int gj0 = k0 + jb + u, gj1 = gj0 + 1;
            float e0 = (gj0 < Nk) ? expf(srow[gj0] - mxv) : 0.f;
            float e1 = (gj1 < Nk) ? expf(srow[gj1] - mxv) : 0.f;
            *(unsigned int*)&Pb[pr][jb + u] = f2bf2(e0, e1);
        }
        __syncthreads();
        // MFMA: wave wid -> dims [wid*16, wid*16+16)
        #pragma unroll
        for (int kc = 0; kc < 4; ++kc) {
            us8v a  = *(const us8v*)&Pb[l15][kc * 32 + lg * 8];
            us8v bf = *(const us8v*)&Vt[wid * 16 + l15][kc * 32 + lg * 8];
            acc = mfma_bf16(a, bf, acc);
        }
        __syncthreads();
    }

    // ---- epilogue: scale by inv-sum, write bf16 ----
    #pragma unroll
    for (int rr = 0; rr < 4; ++rr) {
        int row = lg * 4 + rr;
        float v = acc[rr] * sinv[row];
        o[(size_t)(b * kMC + i0 + row) * kD + h * kDH + wid * 16 + l15] = f2bf(v);
    }
}

// ========================================================================
extern "C" void kernel_launch(void* const* d_in, const int* in_sizes, int n_in,
                              void* d_out, int out_size, void* d_ws, size_t ws_size,
                              hipStream_t stream)
{
    const int*   x   = (const int*)  d_in[0];
    const float* xa  = (const float*)d_in[1];
    const float* tok = (const float*)d_in[4];
    const float* pos = (const float*)d_in[5];
    const float* attn_ln_g  = (const float*)d_in[6];
    const float* attn_ln_b  = (const float*)d_in[7];
    const float* attn_q_w   = (const float*)d_in[8];
    const float* attn_q_b   = (const float*)d_in[9];
    const float* attn_k_w   = (const float*)d_in[10];
    const float* attn_v_w   = (const float*)d_in[11];
    const float* attn_v_b   = (const float*)d_in[12];
    const float* attn_o_w   = (const float*)d_in[13];
    const float* attn_o_b   = (const float*)d_in[14];
    const float* cross_ln_g = (const float*)d_in[15];
    const float* cross_ln_b = (const float*)d_in[16];
    const float* cross_q_w  = (const float*)d_in[17];
    const float* cross_q_b  = (const float*)d_in[18];
    const float* cross_k_w  = (const float*)d_in[19];
    const float* cross_v_w  = (const float*)d_in[20];
    const float* cross_v_b  = (const float*)d_in[21];
    const float* cross_o_w  = (const float*)d_in[22];
    const float* cross_o_b  = (const float*)d_in[23];
    const float* mlp_ln_g   = (const float*)d_in[24];
    const float* mlp_ln_b   = (const float*)d_in[25];
    const float* mlp_w1     = (const float*)d_in[26];
    const float* mlp_b1     = (const float*)d_in[27];
    const float* mlp_w2     = (const float*)d_in[28];
    const float* mlp_b2     = (const float*)d_in[29];
    const float* ln_g       = (const float*)d_in[30];
    const float* ln_b       = (const float*)d_in[31];

    float* out = (float*)d_out;
    float* h    = (float*)d_ws;                          // 512*768 f32
    float* qws  = h   + (size_t)kR * kD;                 // 512*768 f32 (self q)
    float* sS   = qws + (size_t)kR * kD;                 // 24*256*1504 f32
    unsigned short* y16   = (unsigned short*)(sS + (size_t)kB * kH * kMC * kSLDc);
    unsigned short* qb16  = y16  + (size_t)kR * kD;      // cross q bf16
    unsigned short* o16   = qb16 + (size_t)kR * kD;      // attn out bf16
    unsigned short* hid16 = o16  + (size_t)kR * kD;      // MLP hidden bf16
    unsigned short* yF16  = hid16 + (size_t)kR * 4 * kD; // final LN bf16

    k_embed<<<kB * kMC * kD / 256, 256, 0, stream>>>(x, tok, pos, h);

    // all cross K/V projections (layer-invariant input xa) in ONE launch
    {
        GBatch gc{};
        for (int l = 0; l < kL; ++l) {
            gc.e[2 * l]     = { cross_k_w + (size_t)l * kD * kD, nullptr, nullptr,
                                out + OFF_CKV + (size_t)(2 * l) * kSA * kD };
            gc.e[2 * l + 1] = { cross_v_w + (size_t)l * kD * kD, cross_v_b + (size_t)l * kD,
                                nullptr,
                                out + OFF_CKV + (size_t)(2 * l + 1) * kSA * kD };
        }
        gemm_t<0, 0><<<dim3((kSA + 63) / 64, kD / 64, 2 * kL), 256, 0, stream>>>(
            xa, gc, kSA, kD, kD, 0, 1);
    }

    for (int l = 0; l < kL; ++l) {
        size_t dd = (size_t)l * kD * kD;
        float* kbuf  = out + OFF_MKV + (size_t)(2 * l)     * kB * kMC * kD;
        float* vbuf  = out + OFF_MKV + (size_t)(2 * l + 1) * kB * kMC * kD;
        float* ckbuf = out + OFF_CKV + (size_t)(2 * l)     * kSA * kD;
        float* cvbuf = out + OFF_CKV + (size_t)(2 * l + 1) * kSA * kD;
        float* cqk   = out + OFF_CQK + (size_t)l * kB * kH * kT * kSA;

        // --- self attention ---
        k_ln<<<kR, 256, 0, stream>>>(h, attn_ln_g + l * kD, attn_ln_b + l * kD, y16);
        {
            GBatch g3{};
            g3.e[0] = { attn_q_w + dd, attn_q_b + (size_t)l * kD, nullptr, qws };
            g3.e[1] = { attn_k_w + dd, nullptr,                   nullptr, kbuf };
            g3.e[2] = { attn_v_w + dd, attn_v_b + (size_t)l * kD, nullptr, vbuf };
            gemm_t<1, 0><<<dim3(kR / 64, kD / 64, 3), 256, 0, stream>>>(
                y16, g3, kR, kD, kD, 0, 1);
        }
        k_scores<0><<<dim3(kMC / 64, kMC / 64, kB * kH), 256, 0, stream>>>(
            qws, kbuf, sS, nullptr, kMC, kMC, 1, 1);
        k_pv<<<dim3(kMC / 16, kB * kH), 256, 0, stream>>>(sS, vbuf, o16, kMC, kMC, 1);
        {
            GBatch g1{};
            g1.e[0] = { attn_o_w + dd, attn_o_b + (size_t)l * kD, h, h };
            gemm_t<1, 0><<<dim3(kR / 64, kD / 64, 1), 256, 0, stream>>>(
                o16, g1, kR, kD, kD, 0, 1);
        }

        // --- cross attention ---
        k_ln<<<kR, 256, 0, stream>>>(h, cross_ln_g + l * kD, cross_ln_b + l * kD, y16);
        {
            GBatch g1{};
            g1.e[0] = { cross_q_w + dd, cross_q_b + (size_t)l * kD, nullptr, qb16 };
            gemm_t<1, 1><<<dim3(kR / 64, kD / 64, 1), 256, 0, stream>>>(
                y16, g1, kR, kD, kD, 0, 1);
        }
        k_scores<1><<<dim3(kMC / 64, (kSA + 63) / 64, kB * kH), 256, 0, stream>>>(
            qb16, ckbuf, sS, cqk, kSA, kSLDc, 0, 0);
        k_pv<<<dim3(kMC / 16, kB * kH), 256, 0, stream>>>(sS, cvbuf, o16, kSA, kSLDc, 0);
        {
            GBatch g1{};
            g1.e[0] = { cross_o_w + dd, cross_o_b + (size_t)l * kD, h, h };
            gemm_t<1, 0><<<dim3(kR / 64, kD / 64, 1), 256, 0, stream>>>(
                o16, g1, kR, kD, kD, 0, 1);
        }

        // --- MLP ---
        k_ln<<<kR, 256, 0, stream>>>(h, mlp_ln_g + l * kD, mlp_ln_b + l * kD, y16);
        {
            GBatch g1{};
            g1.e[0] = { mlp_w1 + (size_t)l * 4 * kD * kD, mlp_b1 + (size_t)l * 4 * kD,
                        nullptr, hid16 };
            gemm_t<1, 1><<<dim3(kR / 64, 4 * kD / 64, 1), 256, 0, stream>>>(
                y16, g1, kR, 4 * kD, kD, 1, 1);
        }
        {
            GBatch g1{};
            g1.e[0] = { mlp_w2 + (size_t)l * 4 * kD * kD, mlp_b2 + (size_t)l * kD, h, h };
            gemm_t<1, 0><<<dim3(kR / 64, kD / 64, 1), 256, 0, stream>>>(
                hid16, g1, kR, kD, 4 * kD, 0, 1);
        }
    }

    k_finalln<<<kB * kT, 256, 0, stream>>>(h, ln_g, ln_b, yF16);
    {
        // logits: 6 in-block M-tiles so each block streams tok_emb once
        GBatch g1{};
        g1.e[0] = { tok, nullptr, nullptr, out };
        gemm_t<1, 0><<<dim3(1, (kV + 63) / 64, 1), 256, 0, stream>>>(
            yF16, g1, kB * kT, kV, kD, 0, 6);
    }
}